// Round 11
// baseline (425.475 us; speedup 1.0000x reference)
//
#include <hip/hip_runtime.h>

#define N_NODES 100000
#define N_EDGES 3200000
#define D_FEAT 256
#define HIDDEN 16
#define OUT 256
#define N_TILES 1563          // ceil(N_NODES/64); last tile ragged (32 valid)
#define G_HAGG 6250           // N_NODES*16/256
#define EDGE_BLOCKS 100000    // N_EDGES*8/256

typedef __attribute__((ext_vector_type(8))) _Float16 half8;
typedef __attribute__((ext_vector_type(4))) float f32x4;

__device__ __forceinline__ unsigned umax32(unsigned a, unsigned b) { return a > b ? a : b; }

// Monotone f16-bits <-> u16 mapping: encoded compare == float compare (no NaNs here).
__device__ __forceinline__ unsigned short enc16(unsigned short u) {
    return (u & 0x8000) ? (unsigned short)~u : (unsigned short)(u | 0x8000);
}
__device__ __forceinline__ _Float16 dec16(unsigned short e) {
    if (e == 0) return (_Float16)0.f;   // sentinel: no in-edge -> 0
    unsigned short b = (e & 0x8000) ? (unsigned short)(e & 0x7FFF) : (unsigned short)~e;
    return __builtin_bit_cast(_Float16, b);
}

// Kernel 1 (R4-exact + weight-pack blocks): h_agg = x @ W_agg + b_agg (fp32),
// emit packed encoded hpk [node][8] u32, zeroed aenc, x cast to f16 (xh).
// Blocks >= G_HAGG pack W_node/W_neigh into MFMA B-fragment layout.
__global__ __launch_bounds__(256) void k_hagg(
    const float* __restrict__ x, const float* __restrict__ W_agg,
    const float* __restrict__ b_agg, unsigned* __restrict__ hpk,
    unsigned* __restrict__ aenc, _Float16* __restrict__ xh,
    const float* __restrict__ Wn, const float* __restrict__ Wng,
    _Float16* __restrict__ Wp, _Float16* __restrict__ Wnp)
{
    int t = threadIdx.x;
    if (blockIdx.x >= G_HAGG) {
        int id = (blockIdx.x - G_HAGG) * 256 + t;
        if (id < 8192) {                       // W_node: 16 nb x 8 kb x 64 lanes
            int l = id & 63, kb = (id >> 6) & 7, nb = id >> 9;
            int col = nb * 16 + (l & 15);
            int k0 = kb * 32 + (l >> 4) * 8;
            half8 v;
            #pragma unroll
            for (int j = 0; j < 8; ++j) v[j] = (_Float16)Wn[(size_t)(k0 + j) * OUT + col];
            ((half8*)Wp)[id] = v;
        } else if (id < 9216) {                // W_neigh: 16 nb x 64 lanes (K=32 pad)
            int id2 = id - 8192;
            int l = id2 & 63, nb = id2 >> 6;
            int col = nb * 16 + (l & 15);
            int k0 = (l >> 4) * 8;
            half8 v;
            #pragma unroll
            for (int j = 0; j < 8; ++j) {
                int k = k0 + j;
                v[j] = (k < HIDDEN) ? (_Float16)Wng[(size_t)k * OUT + col] : (_Float16)0.f;
            }
            ((half8*)Wnp)[id2] = v;
        }
        return;
    }

    __shared__ float WlT[HIDDEN * 260];   // [k][d], row stride 260 floats
    for (int i = t; i < D_FEAT * HIDDEN; i += 256)
        WlT[(i & 15) * 260 + (i >> 4)] = W_agg[i];
    __syncthreads();

    int gid = blockIdx.x * 256 + t;
    int node = gid >> 4, k = gid & 15;

    const float4* x4 = (const float4*)(x + (size_t)node * D_FEAT);
    const float4* wt4 = (const float4*)(WlT + k * 260);
    float acc = b_agg[k];
    #pragma unroll 8
    for (int dv = 0; dv < D_FEAT / 4; ++dv) {
        float4 xv = x4[dv];
        float4 wv = wt4[dv];
        acc = fmaf(xv.x, wv.x, acc);
        acc = fmaf(xv.y, wv.y, acc);
        acc = fmaf(xv.z, wv.z, acc);
        acc = fmaf(xv.w, wv.w, acc);
    }

    unsigned short e16 = enc16(__builtin_bit_cast(unsigned short, (_Float16)acc));
    unsigned other = (unsigned)__shfl_xor((int)e16, 1);
    if ((k & 1) == 0) {
        unsigned word = (unsigned)e16 | (other << 16);
        size_t idx = (size_t)node * 8 + (k >> 1);
        hpk[idx] = word;
        aenc[idx] = 0u;
    }

    // f16 conversion of this thread's 16-element slice of the row (L1-hot).
    const float4* xr4 = x4 + k * 4;
    float4 c0 = xr4[0], c1 = xr4[1], c2 = xr4[2], c3 = xr4[3];
    half8 lo, hi;
    lo[0]=(_Float16)c0.x; lo[1]=(_Float16)c0.y; lo[2]=(_Float16)c0.z; lo[3]=(_Float16)c0.w;
    lo[4]=(_Float16)c1.x; lo[5]=(_Float16)c1.y; lo[6]=(_Float16)c1.z; lo[7]=(_Float16)c1.w;
    hi[0]=(_Float16)c2.x; hi[1]=(_Float16)c2.y; hi[2]=(_Float16)c2.z; hi[3]=(_Float16)c2.w;
    hi[4]=(_Float16)c3.x; hi[5]=(_Float16)c3.y; hi[6]=(_Float16)c3.z; hi[7]=(_Float16)c3.w;
    half8* xo = (half8*)(xh + (size_t)node * D_FEAT + k * 16);
    xo[0] = lo; xo[1] = hi;
}

// Kernel 2 (fused): blocks [0, N_TILES) = h-GEMM tiles (xh @ W_node + b_node ->
// packed f16, through-L2 stores, h parked in out's neigh-half / hlast);
// blocks [N_TILES, ...) = R4-exact edge segment-max (u32 CAS, 8 lanes/edge).
// GEMM work hides inside the edge kernel's memory-side-atomic-bound window.
__global__ __launch_bounds__(256) void k_fused(
    const _Float16* __restrict__ xh, const _Float16* __restrict__ Wp,
    const float* __restrict__ b_node,
    const int* __restrict__ src, const int* __restrict__ dst,
    const unsigned* __restrict__ hpk, unsigned* __restrict__ aenc,
    _Float16* __restrict__ hlast, float* __restrict__ out)
{
    int t = threadIdx.x;
    if (blockIdx.x >= N_TILES) {
        // ---- edge path (R4-exact): pre-check + packed u32 CAS
        int tid = (blockIdx.x - N_TILES) * 256 + t;
        int e = tid >> 3, p = tid & 7;
        int s = src[e], d = dst[e];
        unsigned mine = hpk[(size_t)s * 8 + p];
        unsigned* addr = aenc + (size_t)d * 8 + p;

        unsigned cur = *addr;
        unsigned lo = umax32(cur & 0xFFFFu, mine & 0xFFFFu);
        unsigned hi = umax32(cur >> 16, mine >> 16);
        unsigned nv = lo | (hi << 16);
        while (nv != cur) {
            unsigned old = atomicCAS(addr, cur, nv);
            if (old == cur) break;
            cur = old;
            lo = umax32(cur & 0xFFFFu, mine & 0xFFFFu);
            hi = umax32(cur >> 16, mine >> 16);
            nv = lo | (hi << 16);
        }
        return;
    }

    // ---- GEMM tile path: h = xh @ W_node + b_node for 64 nodes, packed f16
    int tile = blockIdx.x;
    int base = tile * 64;
    int w = t >> 6, l = t & 63, lr = l & 15, lg = l >> 4;

    f32x4 acc[4][4];
    #pragma unroll
    for (int mb = 0; mb < 4; ++mb)
        #pragma unroll
        for (int nb = 0; nb < 4; ++nb) acc[mb][nb] = (f32x4){0.f, 0.f, 0.f, 0.f};

    size_t arow[4];
    #pragma unroll
    for (int mb = 0; mb < 4; ++mb) {
        int node = base + mb * 16 + lr;
        if (node > N_NODES - 1) node = N_NODES - 1;
        arow[mb] = (size_t)node * D_FEAT + lg * 8;
    }

    const half8* WpV = (const half8*)Wp;
    #pragma unroll
    for (int kb = 0; kb < 8; ++kb) {
        half8 a[4], b[4];
        #pragma unroll
        for (int mb = 0; mb < 4; ++mb)
            a[mb] = *(const half8*)(xh + arow[mb] + kb * 32);
        #pragma unroll
        for (int nb = 0; nb < 4; ++nb)
            b[nb] = WpV[((w * 4 + nb) * 8 + kb) * 64 + l];
        #pragma unroll
        for (int mb = 0; mb < 4; ++mb)
            #pragma unroll
            for (int nb = 0; nb < 4; ++nb)
                acc[mb][nb] = __builtin_amdgcn_mfma_f32_16x16x32_f16(
                    a[mb], b[nb], acc[mb][nb], 0, 0, 0);
    }

    float bnc[4];
    #pragma unroll
    for (int nb = 0; nb < 4; ++nb) bnc[nb] = b_node[w * 64 + nb * 16 + lr];

    half8 hv8[8];
    #pragma unroll
    for (int mb = 0; mb < 4; ++mb)
        #pragma unroll
        for (int nb = 0; nb < 4; ++nb)
            #pragma unroll
            for (int r = 0; r < 4; ++r) {
                int idx = mb * 16 + nb * 4 + r;
                hv8[idx >> 3][idx & 7] = (_Float16)(acc[mb][nb][r] + bnc[nb]);
            }

    char* hb;
    if (tile == N_TILES - 1) hb = (char*)hlast + (size_t)t * 128;
    else hb = (char*)out + (size_t)(base + (t >> 2)) * 2048 + 1024 + (size_t)(t & 3) * 128;
    #pragma unroll
    for (int i = 0; i < 8; ++i)
        ((half8*)hb)[i] = hv8[i];
}

// K3 (R7-exact epilogue): load packed h, neighbour MFMA from aenc, l2-normalize.
__global__ __launch_bounds__(256) void k_epi(
    const unsigned* __restrict__ aenc, const _Float16* __restrict__ Wnp,
    const float* __restrict__ b_neigh, const _Float16* __restrict__ hlast,
    float* __restrict__ out)
{
    __shared__ _Float16 aggL[64][40];
    __shared__ float ss[4][64];
    __shared__ float invl[64];

    int t = threadIdx.x;
    int w = t >> 6, l = t & 63, lr = l & 15, lg = l >> 4;
    int tile = blockIdx.x;
    int base = tile * 64;

    // stage + decode agg tile
    for (int i = t; i < 64 * 8; i += 256) {
        int nl = i >> 3, p = i & 7;
        int gn = base + nl;
        unsigned v = (gn < N_NODES) ? aenc[(size_t)gn * 8 + p] : 0u;
        aggL[nl][2 * p]     = dec16((unsigned short)(v & 0xFFFFu));
        aggL[nl][2 * p + 1] = dec16((unsigned short)(v >> 16));
    }
    for (int i = t; i < 64 * 16; i += 256)
        aggL[i >> 4][16 + (i & 15)] = (_Float16)0.f;

    // this thread's packed h (written by k_fused thread t of same tile)
    const char* hb;
    if (tile == N_TILES - 1) hb = (const char*)hlast + (size_t)t * 128;
    else hb = (const char*)out + (size_t)(base + (t >> 2)) * 2048 + 1024 + (size_t)(t & 3) * 128;
    half8 hv8[8];
    #pragma unroll
    for (int i = 0; i < 8; ++i)
        hv8[i] = ((const half8*)hb)[i];

    __syncthreads();

    // neighbour layer: one MFMA per (mb,nb), K=32 (upper 16 zero-padded)
    f32x4 nacc[4][4];
    {
        half8 an[4], bn[4];
        #pragma unroll
        for (int mb = 0; mb < 4; ++mb)
            an[mb] = *(const half8*)(&aggL[mb * 16 + lr][lg * 8]);
        #pragma unroll
        for (int nb = 0; nb < 4; ++nb)
            bn[nb] = ((const half8*)Wnp)[(w * 4 + nb) * 64 + l];
        f32x4 z = (f32x4){0.f, 0.f, 0.f, 0.f};
        #pragma unroll
        for (int mb = 0; mb < 4; ++mb)
            #pragma unroll
            for (int nb = 0; nb < 4; ++nb)
                nacc[mb][nb] = __builtin_amdgcn_mfma_f32_16x16x32_f16(
                    an[mb], bn[nb], z, 0, 0, 0);
    }

    float bec[4];
    #pragma unroll
    for (int nb = 0; nb < 4; ++nb) bec[nb] = b_neigh[w * 64 + nb * 16 + lr];
    #pragma unroll
    for (int mb = 0; mb < 4; ++mb)
        #pragma unroll
        for (int nb = 0; nb < 4; ++nb)
            #pragma unroll
            for (int r = 0; r < 4; ++r)
                nacc[mb][nb][r] += bec[nb];

    // sum of squares per node row
    #pragma unroll
    for (int mb = 0; mb < 4; ++mb) {
        float p[4] = {0.f, 0.f, 0.f, 0.f};
        #pragma unroll
        for (int nb = 0; nb < 4; ++nb)
            #pragma unroll
            for (int r = 0; r < 4; ++r) {
                int idx = mb * 16 + nb * 4 + r;
                float hf = (float)hv8[idx >> 3][idx & 7];
                p[r] += hf * hf + nacc[mb][nb][r] * nacc[mb][nb][r];
            }
        #pragma unroll
        for (int r = 0; r < 4; ++r) {
            float v = p[r];
            v += __shfl_xor(v, 1);
            v += __shfl_xor(v, 2);
            v += __shfl_xor(v, 4);
            v += __shfl_xor(v, 8);
            if (lr == 0) ss[w][mb * 16 + lg * 4 + r] = v;
        }
    }
    __syncthreads();
    if (t < 64) {
        float sq = ss[0][t] + ss[1][t] + ss[2][t] + ss[3][t];
        invl[t] = rsqrtf(fmaxf(sq, 1e-12f));
    }
    __syncthreads();

    #pragma unroll
    for (int mb = 0; mb < 4; ++mb)
        #pragma unroll
        for (int r = 0; r < 4; ++r) {
            int slot = mb * 16 + lg * 4 + r;
            int node = base + slot;
            if (node < N_NODES) {
                float inv = invl[slot];
                size_t row = (size_t)node * (2 * OUT);
                #pragma unroll
                for (int nb = 0; nb < 4; ++nb) {
                    int col = w * 64 + nb * 16 + lr;
                    int idx = mb * 16 + nb * 4 + r;
                    out[row + col] = (float)hv8[idx >> 3][idx & 7] * inv;
                    out[row + OUT + col] = nacc[mb][nb][r] * inv;
                }
            }
        }
}

extern "C" void kernel_launch(void* const* d_in, const int* in_sizes, int n_in,
                              void* d_out, int out_size, void* d_ws, size_t ws_size,
                              hipStream_t stream) {
    const float* x       = (const float*)d_in[0];
    const int*   src     = (const int*)d_in[1];
    const int*   dst     = (const int*)d_in[2];
    const float* W_node  = (const float*)d_in[3];
    const float* b_node  = (const float*)d_in[4];
    const float* W_agg   = (const float*)d_in[5];
    const float* b_agg   = (const float*)d_in[6];
    const float* W_neigh = (const float*)d_in[7];
    const float* b_neigh = (const float*)d_in[8];
    float* out = (float*)d_out;

    char* ws = (char*)d_ws;
    unsigned*  hpk   = (unsigned*)ws;      ws += (size_t)N_NODES * 8 * 4;
    unsigned*  aenc  = (unsigned*)ws;      ws += (size_t)N_NODES * 8 * 4;
    _Float16*  Wp    = (_Float16*)ws;      ws += (size_t)16 * 8 * 64 * 8 * 2;
    _Float16*  Wnp   = (_Float16*)ws;      ws += (size_t)16 * 64 * 8 * 2;
    _Float16*  hlast = (_Float16*)ws;      ws += (size_t)256 * 64 * 2;   // 32 KB
    _Float16*  xh    = (_Float16*)ws;      // 51.2 MB

    k_hagg<<<G_HAGG + 36, 256, 0, stream>>>(x, W_agg, b_agg, hpk, aenc, xh,
                                            W_node, W_neigh, Wp, Wnp);

    k_fused<<<N_TILES + EDGE_BLOCKS, 256, 0, stream>>>(
        xh, Wp, b_node, src, dst, hpk, aenc, hlast, out);

    k_epi<<<N_TILES, 256, 0, stream>>>(aenc, Wnp, b_neigh, hlast, out);
}

// Round 13
// 282.520 us; speedup vs baseline: 1.5060x; 1.5060x over previous
//
#include <hip/hip_runtime.h>

#define N_NODES 100000
#define N_EDGES 3200000
#define D_FEAT 256
#define HIDDEN 16
#define OUT 256
#define N_TILES 1563                  // ceil(N_NODES/64); last tile ragged
#define PLANE ((size_t)N_NODES * 8)   // u32 words per aenc plane
#define NBUK 196                      // node buckets of 512
#define BSZ 512
#define CAP_G 20480                   // per-bucket global list capacity (mean 16.3K)
#define NPLANE 4                      // k_bucket planes; plane 4 = CAS fallback

typedef __attribute__((ext_vector_type(8))) _Float16 half8;
typedef __attribute__((ext_vector_type(4))) float f32x4;

__device__ __forceinline__ unsigned umax32(unsigned a, unsigned b) { return a > b ? a : b; }
__device__ __forceinline__ unsigned pmax16x2(unsigned a, unsigned b) {
    return umax32(a & 0xFFFFu, b & 0xFFFFu) | (umax32(a >> 16, b >> 16) << 16);
}

// Monotone f16-bits <-> u16 mapping: encoded compare == float compare.
__device__ __forceinline__ unsigned short enc16(unsigned short u) {
    return (u & 0x8000) ? (unsigned short)~u : (unsigned short)(u | 0x8000);
}
__device__ __forceinline__ _Float16 dec16(unsigned short e) {
    if (e == 0) return (_Float16)0.f;   // sentinel: no in-edge -> 0
    unsigned short b = (e & 0x8000) ? (unsigned short)(e & 0x7FFF) : (unsigned short)~e;
    return __builtin_bit_cast(_Float16, b);
}

// Rare-path: correct device-scope CAS-max into fallback plane 4.
__device__ __noinline__ void fb_cas(const unsigned* hpk, unsigned* a4, int sv, int dv) {
    #pragma unroll
    for (int p = 0; p < 8; ++p) {
        unsigned mine = hpk[(size_t)sv * 8 + p];
        unsigned* addr = a4 + (size_t)dv * 8 + p;
        unsigned cur = *addr;
        unsigned nv = pmax16x2(cur, mine);
        while (nv != cur) {
            unsigned old = atomicCAS(addr, cur, nv);
            if (old == cur) break;
            cur = old;
            nv = pmax16x2(cur, mine);
        }
    }
}

// Pack W_node, W_neigh, W_agg into MFMA B-fragment layout (f16). 38 blocks.
__global__ void k_pack(const float* __restrict__ Wn, const float* __restrict__ Wng,
                       const float* __restrict__ Wag,
                       _Float16* __restrict__ Wp, _Float16* __restrict__ Wnp,
                       _Float16* __restrict__ Wap)
{
    int id = blockIdx.x * 256 + threadIdx.x;
    if (id < 8192) {                       // W_node: 16 nb x 8 kb x 64 lanes
        int l = id & 63, kb = (id >> 6) & 7, nb = id >> 9;
        int col = nb * 16 + (l & 15);
        int k0 = kb * 32 + (l >> 4) * 8;
        half8 v;
        #pragma unroll
        for (int j = 0; j < 8; ++j) v[j] = (_Float16)Wn[(size_t)(k0 + j) * OUT + col];
        ((half8*)Wp)[id] = v;
    } else if (id < 9216) {                // W_neigh: 16 nb x 64 lanes (K=32 pad)
        int id2 = id - 8192;
        int l = id2 & 63, nb = id2 >> 6;
        int col = nb * 16 + (l & 15);
        int k0 = (l >> 4) * 8;
        half8 v;
        #pragma unroll
        for (int j = 0; j < 8; ++j) {
            int k = k0 + j;
            v[j] = (k < HIDDEN) ? (_Float16)Wng[(size_t)k * OUT + col] : (_Float16)0.f;
        }
        ((half8*)Wnp)[id2] = v;
    } else if (id < 9728) {                // W_agg: 1 nb (16 cols) x 8 kb x 64 lanes
        int id3 = id - 9216;
        int l = id3 & 63, kb = id3 >> 6;
        int col = l & 15;
        int k0 = kb * 32 + (l >> 4) * 8;
        half8 v;
        #pragma unroll
        for (int j = 0; j < 8; ++j) v[j] = (_Float16)Wag[(size_t)(k0 + j) * HIDDEN + col];
        ((half8*)Wap)[id3] = v;
    }
}

// K1 (R7 structure): per 64-node tile, MFMA h = x@W_node (+bias -> packed f16,
// parked in out's neigh half / hlast) AND h_agg = x@W_agg (wave 0 -> hpk, zero
// fallback plane 4). Also zeroes gcnt (block 0). x read once f32 -> f16 in regs.
__global__ __launch_bounds__(256) void k_gemm(
    const float* __restrict__ x, const _Float16* __restrict__ Wp,
    const _Float16* __restrict__ Wap, const float* __restrict__ b_node,
    const float* __restrict__ b_agg, unsigned* __restrict__ hpk,
    unsigned* __restrict__ aencP, unsigned* __restrict__ gcnt,
    _Float16* __restrict__ hlast, float* __restrict__ out)
{
    __shared__ unsigned short eagg[64][18];

    int t = threadIdx.x;
    if (blockIdx.x == 0 && t < NBUK) gcnt[t] = 0u;

    int w = t >> 6, l = t & 63, lr = l & 15, lg = l >> 4;
    int base = blockIdx.x * 64;

    size_t arow[4];
    #pragma unroll
    for (int mb = 0; mb < 4; ++mb) {
        int node = base + mb * 16 + lr;
        if (node > N_NODES - 1) node = N_NODES - 1;
        arow[mb] = (size_t)node * D_FEAT + lg * 8;
    }

    f32x4 acc[4][4];
    #pragma unroll
    for (int mb = 0; mb < 4; ++mb)
        #pragma unroll
        for (int nb = 0; nb < 4; ++nb) acc[mb][nb] = (f32x4){0.f, 0.f, 0.f, 0.f};
    f32x4 agga[4];
    #pragma unroll
    for (int mb = 0; mb < 4; ++mb) agga[mb] = (f32x4){0.f, 0.f, 0.f, 0.f};

    const half8* WpV = (const half8*)Wp;
    const half8* WaV = (const half8*)Wap;

    #pragma unroll
    for (int kb = 0; kb < 8; ++kb) {
        half8 a[4];
        #pragma unroll
        for (int mb = 0; mb < 4; ++mb) {
            const float4* p = (const float4*)(x + arow[mb] + kb * 32);
            float4 u = p[0], v = p[1];
            half8 h;
            h[0]=(_Float16)u.x; h[1]=(_Float16)u.y; h[2]=(_Float16)u.z; h[3]=(_Float16)u.w;
            h[4]=(_Float16)v.x; h[5]=(_Float16)v.y; h[6]=(_Float16)v.z; h[7]=(_Float16)v.w;
            a[mb] = h;
        }
        half8 b[4];
        #pragma unroll
        for (int nb = 0; nb < 4; ++nb)
            b[nb] = WpV[((w * 4 + nb) * 8 + kb) * 64 + l];
        if (w == 0) {
            half8 bg = WaV[kb * 64 + l];
            #pragma unroll
            for (int mb = 0; mb < 4; ++mb)
                agga[mb] = __builtin_amdgcn_mfma_f32_16x16x32_f16(a[mb], bg, agga[mb], 0, 0, 0);
        }
        #pragma unroll
        for (int mb = 0; mb < 4; ++mb)
            #pragma unroll
            for (int nb = 0; nb < 4; ++nb)
                acc[mb][nb] = __builtin_amdgcn_mfma_f32_16x16x32_f16(
                    a[mb], b[nb], acc[mb][nb], 0, 0, 0);
    }

    // wave 0: bias + encode h_agg into LDS
    if (w == 0) {
        float ba = b_agg[lr];
        #pragma unroll
        for (int mb = 0; mb < 4; ++mb)
            #pragma unroll
            for (int r = 0; r < 4; ++r) {
                float val = agga[mb][r] + ba;
                eagg[mb * 16 + lg * 4 + r][lr] =
                    enc16(__builtin_bit_cast(unsigned short, (_Float16)val));
            }
    }
    __syncthreads();

    // pack pairs -> hpk; zero fallback plane 4
    #pragma unroll
    for (int q = 0; q < 2; ++q) {
        int wd = t * 2 + q;
        int node = wd >> 3, p = wd & 7;
        int gn = base + node;
        if (gn < N_NODES) {
            unsigned lo = eagg[node][2 * p], hi = eagg[node][2 * p + 1];
            unsigned word = lo | (hi << 16);
            size_t idx = (size_t)gn * 8 + p;
            hpk[idx] = word;
            aencP[(size_t)NPLANE * PLANE + idx] = 0u;
        }
    }

    // bias + pack h to f16, park in out's neigh half (through-L2; R11-proven)
    float bnc[4];
    #pragma unroll
    for (int nb = 0; nb < 4; ++nb) bnc[nb] = b_node[w * 64 + nb * 16 + lr];
    half8 hv8[8];
    #pragma unroll
    for (int mb = 0; mb < 4; ++mb)
        #pragma unroll
        for (int nb = 0; nb < 4; ++nb)
            #pragma unroll
            for (int r = 0; r < 4; ++r) {
                int idx = mb * 16 + nb * 4 + r;
                hv8[idx >> 3][idx & 7] = (_Float16)(acc[mb][nb][r] + bnc[nb]);
            }
    char* hb;
    if (blockIdx.x == N_TILES - 1) hb = (char*)hlast + (size_t)t * 128;
    else hb = (char*)out + (size_t)(base + (t >> 2)) * 2048 + 1024 + (size_t)(t & 3) * 128;
    #pragma unroll
    for (int i = 0; i < 8; ++i)
        ((half8*)hb)[i] = hv8[i];
}

// Phase 1: bin edges into 196 per-bucket global lists via LDS staging.
// Entry u32 = src<<9 | (dst & 511). 800 blocks x 4000 edges.
__global__ __launch_bounds__(256) void k_bin(
    const int* __restrict__ src, const int* __restrict__ dst,
    const unsigned* __restrict__ hpk,
    unsigned* __restrict__ gbin, unsigned* __restrict__ gcnt,
    unsigned* __restrict__ a4)
{
    __shared__ unsigned lbuf[NBUK * 64];   // 50 KB
    __shared__ unsigned lcnt[NBUK];
    __shared__ unsigned gbase[NBUK];
    int t = threadIdx.x;
    for (int i = t; i < NBUK; i += 256) lcnt[i] = 0u;
    __syncthreads();

    int start = blockIdx.x * 4000;
    #pragma unroll 4
    for (int it = 0; it < 16; ++it) {
        int j = it * 256 + t;
        if (j < 4000) {
            int idx = start + j;
            int sv = src[idx], dv = dst[idx];
            int bk = dv >> 9;
            unsigned ev = ((unsigned)sv << 9) | (unsigned)(dv & 511);
            unsigned r = atomicAdd(&lcnt[bk], 1u);
            if (r < 64) lbuf[bk * 64 + r] = ev;
            else fb_cas(hpk, a4, sv, dv);      // ~1e-13 probability path
        }
    }
    __syncthreads();

    if (t < NBUK) {
        unsigned c = lcnt[t]; if (c > 64) c = 64;
        gbase[t] = atomicAdd(&gcnt[t], c);
    }
    __syncthreads();

    int wv = t >> 6, ln = t & 63;
    for (int b = wv; b < NBUK; b += 4) {
        unsigned c = lcnt[b]; if (c > 64) c = 64;
        if (ln < (int)c) {
            unsigned pos = gbase[b] + (unsigned)ln;
            unsigned ev = lbuf[b * 64 + ln];
            if (pos < CAP_G) gbin[(size_t)b * CAP_G + pos] = ev;
            else fb_cas(hpk, a4, (int)(ev >> 9), b * BSZ + (int)(ev & 511));
        }
    }
}

// Phase 2: per (bucket, plane) block — LDS segment-max. Gather hpk (L2-resident,
// read-only), atomicMax in LDS (17-padded), write plane coalesced. NO global atomics.
__global__ __launch_bounds__(256) void k_bucket(
    const unsigned* __restrict__ gbin, const unsigned* __restrict__ gcnt,
    const unsigned* __restrict__ hpk, unsigned* __restrict__ aencP)
{
    __shared__ unsigned tab[BSZ * 17];   // 34.8 KB
    int t = threadIdx.x;
    int b = blockIdx.x % NBUK;
    int k = blockIdx.x / NBUK;           // 0..3
    for (int i = t; i < BSZ * 17; i += 256) tab[i] = 0u;
    __syncthreads();

    int cnt = (int)gcnt[b]; if (cnt > CAP_G) cnt = CAP_G;
    int s = (cnt * k) >> 2;
    int e = (cnt * (k + 1)) >> 2;
    int p = t & 7;
    for (int i = s + (t >> 3); i < e; i += 32) {
        unsigned ev = gbin[(size_t)b * CAP_G + i];
        int srcn = (int)(ev >> 9), ld = (int)(ev & 511);
        unsigned pair = hpk[(size_t)srcn * 8 + p];
        atomicMax(&tab[ld * 17 + 2 * p], pair & 0xFFFFu);
        atomicMax(&tab[ld * 17 + 2 * p + 1], pair >> 16);
    }
    __syncthreads();

    for (int j = t; j < BSZ * 8; j += 256) {
        int n = j >> 3, pp = j & 7;
        int gn = b * BSZ + n;
        if (gn < N_NODES) {
            unsigned wd = tab[n * 17 + 2 * pp] | (tab[n * 17 + 2 * pp + 1] << 16);
            aencP[(size_t)k * PLANE + (size_t)gn * 8 + pp] = wd;
        }
    }
}

// K3: merge 5 planes, decode agg -> LDS, load parked h, neighbour MFMA, normalize.
__global__ __launch_bounds__(256) void k_epi(
    const unsigned* __restrict__ aencP, const _Float16* __restrict__ Wnp,
    const float* __restrict__ b_neigh, const _Float16* __restrict__ hlast,
    float* __restrict__ out)
{
    __shared__ _Float16 aggL[64][40];
    __shared__ float ss[4][64];
    __shared__ float invl[64];

    int t = threadIdx.x;
    int w = t >> 6, l = t & 63, lr = l & 15, lg = l >> 4;
    int tile = blockIdx.x;
    int base = tile * 64;

    for (int i = t; i < 64 * 8; i += 256) {
        int nl = i >> 3, p = i & 7;
        int gn = base + nl;
        unsigned v = 0u;
        if (gn < N_NODES) {
            size_t idx = (size_t)gn * 8 + p;
            #pragma unroll
            for (int k5 = 0; k5 <= NPLANE; ++k5)
                v = pmax16x2(v, aencP[(size_t)k5 * PLANE + idx]);
        }
        aggL[nl][2 * p]     = dec16((unsigned short)(v & 0xFFFFu));
        aggL[nl][2 * p + 1] = dec16((unsigned short)(v >> 16));
    }
    for (int i = t; i < 64 * 16; i += 256)
        aggL[i >> 4][16 + (i & 15)] = (_Float16)0.f;

    const char* hb;
    if (tile == N_TILES - 1) hb = (const char*)hlast + (size_t)t * 128;
    else hb = (const char*)out + (size_t)(base + (t >> 2)) * 2048 + 1024 + (size_t)(t & 3) * 128;
    half8 hv8[8];
    #pragma unroll
    for (int i = 0; i < 8; ++i)
        hv8[i] = ((const half8*)hb)[i];

    __syncthreads();

    f32x4 nacc[4][4];
    {
        half8 an[4], bn[4];
        #pragma unroll
        for (int mb = 0; mb < 4; ++mb)
            an[mb] = *(const half8*)(&aggL[mb * 16 + lr][lg * 8]);
        #pragma unroll
        for (int nb = 0; nb < 4; ++nb)
            bn[nb] = ((const half8*)Wnp)[(w * 4 + nb) * 64 + l];
        f32x4 z = (f32x4){0.f, 0.f, 0.f, 0.f};
        #pragma unroll
        for (int mb = 0; mb < 4; ++mb)
            #pragma unroll
            for (int nb = 0; nb < 4; ++nb)
                nacc[mb][nb] = __builtin_amdgcn_mfma_f32_16x16x32_f16(
                    an[mb], bn[nb], z, 0, 0, 0);
    }

    float bec[4];
    #pragma unroll
    for (int nb = 0; nb < 4; ++nb) bec[nb] = b_neigh[w * 64 + nb * 16 + lr];
    #pragma unroll
    for (int mb = 0; mb < 4; ++mb)
        #pragma unroll
        for (int nb = 0; nb < 4; ++nb)
            #pragma unroll
            for (int r = 0; r < 4; ++r)
                nacc[mb][nb][r] += bec[nb];

    #pragma unroll
    for (int mb = 0; mb < 4; ++mb) {
        float p[4] = {0.f, 0.f, 0.f, 0.f};
        #pragma unroll
        for (int nb = 0; nb < 4; ++nb)
            #pragma unroll
            for (int r = 0; r < 4; ++r) {
                int idx = mb * 16 + nb * 4 + r;
                float hf = (float)hv8[idx >> 3][idx & 7];
                p[r] += hf * hf + nacc[mb][nb][r] * nacc[mb][nb][r];
            }
        #pragma unroll
        for (int r = 0; r < 4; ++r) {
            float v = p[r];
            v += __shfl_xor(v, 1);
            v += __shfl_xor(v, 2);
            v += __shfl_xor(v, 4);
            v += __shfl_xor(v, 8);
            if (lr == 0) ss[w][mb * 16 + lg * 4 + r] = v;
        }
    }
    __syncthreads();
    if (t < 64) {
        float sq = ss[0][t] + ss[1][t] + ss[2][t] + ss[3][t];
        invl[t] = rsqrtf(fmaxf(sq, 1e-12f));
    }
    __syncthreads();

    #pragma unroll
    for (int mb = 0; mb < 4; ++mb)
        #pragma unroll
        for (int r = 0; r < 4; ++r) {
            int slot = mb * 16 + lg * 4 + r;
            int node = base + slot;
            if (node < N_NODES) {
                float inv = invl[slot];
                size_t row = (size_t)node * (2 * OUT);
                #pragma unroll
                for (int nb = 0; nb < 4; ++nb) {
                    int col = w * 64 + nb * 16 + lr;
                    int idx = mb * 16 + nb * 4 + r;
                    out[row + col] = (float)hv8[idx >> 3][idx & 7] * inv;
                    out[row + OUT + col] = nacc[mb][nb][r] * inv;
                }
            }
        }
}

extern "C" void kernel_launch(void* const* d_in, const int* in_sizes, int n_in,
                              void* d_out, int out_size, void* d_ws, size_t ws_size,
                              hipStream_t stream) {
    const float* x       = (const float*)d_in[0];
    const int*   src     = (const int*)d_in[1];
    const int*   dst     = (const int*)d_in[2];
    const float* W_node  = (const float*)d_in[3];
    const float* b_node  = (const float*)d_in[4];
    const float* W_agg   = (const float*)d_in[5];
    const float* b_agg   = (const float*)d_in[6];
    const float* W_neigh = (const float*)d_in[7];
    const float* b_neigh = (const float*)d_in[8];
    float* out = (float*)d_out;

    char* ws = (char*)d_ws;
    unsigned*  hpk   = (unsigned*)ws;      ws += (size_t)N_NODES * 8 * 4;          // 3.2 MB
    unsigned*  aencP = (unsigned*)ws;      ws += (size_t)(NPLANE + 1) * PLANE * 4; // 16 MB
    unsigned*  gbin  = (unsigned*)ws;      ws += (size_t)NBUK * CAP_G * 4;         // 16.1 MB
    unsigned*  gcnt  = (unsigned*)ws;      ws += 1024;
    _Float16*  Wp    = (_Float16*)ws;      ws += (size_t)16 * 8 * 64 * 8 * 2;
    _Float16*  Wnp   = (_Float16*)ws;      ws += (size_t)16 * 64 * 8 * 2;
    _Float16*  Wap   = (_Float16*)ws;      ws += (size_t)8 * 64 * 8 * 2;
    _Float16*  hlast = (_Float16*)ws;      // 32 KB

    unsigned* a4 = aencP + (size_t)NPLANE * PLANE;

    k_pack<<<38, 256, 0, stream>>>(W_node, W_neigh, W_agg, Wp, Wnp, Wap);

    k_gemm<<<N_TILES, 256, 0, stream>>>(x, Wp, Wap, b_node, b_agg,
                                        hpk, aencP, gcnt, hlast, out);

    k_bin<<<800, 256, 0, stream>>>(src, dst, hpk, gbin, gcnt, a4);

    k_bucket<<<NBUK * NPLANE, 256, 0, stream>>>(gbin, gcnt, hpk, aencP);

    k_epi<<<N_TILES, 256, 0, stream>>>(aencP, Wnp, b_neigh, hlast, out);
}

// Round 15
// 256.413 us; speedup vs baseline: 1.6593x; 1.1018x over previous
//
#include <hip/hip_runtime.h>

#define N_NODES 100000
#define N_EDGES 3200000
#define D_FEAT 256
#define HIDDEN 16
#define OUT 256
#define N_TILES 3125                  // N_NODES / 32 exactly
#define PLANE ((size_t)N_NODES * 8)   // u32 words per aenc plane
#define NBUK 196                      // node buckets of 512
#define BSZ 512
#define CAP_G 20480                   // per-bucket global list capacity (mean 16.3K)
#define NPLANE 4                      // k_bucket planes; plane 4 = CAS fallback

typedef __attribute__((ext_vector_type(8))) _Float16 half8;
typedef __attribute__((ext_vector_type(4))) float f32x4;

__device__ __forceinline__ unsigned umax32(unsigned a, unsigned b) { return a > b ? a : b; }
__device__ __forceinline__ unsigned pmax16x2(unsigned a, unsigned b) {
    return umax32(a & 0xFFFFu, b & 0xFFFFu) | (umax32(a >> 16, b >> 16) << 16);
}

// Monotone f16-bits <-> u16 mapping: encoded compare == float compare.
__device__ __forceinline__ unsigned short enc16(unsigned short u) {
    return (u & 0x8000) ? (unsigned short)~u : (unsigned short)(u | 0x8000);
}
__device__ __forceinline__ _Float16 dec16(unsigned short e) {
    if (e == 0) return (_Float16)0.f;   // sentinel: no in-edge -> 0
    unsigned short b = (e & 0x8000) ? (unsigned short)(e & 0x7FFF) : (unsigned short)~e;
    return __builtin_bit_cast(_Float16, b);
}

// Rare-path: correct device-scope CAS-max into fallback plane 4.
__device__ __noinline__ void fb_cas(const unsigned* hpk, unsigned* a4, int sv, int dv) {
    #pragma unroll
    for (int p = 0; p < 8; ++p) {
        unsigned mine = hpk[(size_t)sv * 8 + p];
        unsigned* addr = a4 + (size_t)dv * 8 + p;
        unsigned cur = *addr;
        unsigned nv = pmax16x2(cur, mine);
        while (nv != cur) {
            unsigned old = atomicCAS(addr, cur, nv);
            if (old == cur) break;
            cur = old;
            nv = pmax16x2(cur, mine);
        }
    }
}

// Pack W_node, W_neigh, W_agg into MFMA B-fragment layout (f16). 38 blocks.
__global__ void k_pack(const float* __restrict__ Wn, const float* __restrict__ Wng,
                       const float* __restrict__ Wag,
                       _Float16* __restrict__ Wp, _Float16* __restrict__ Wnp,
                       _Float16* __restrict__ Wap)
{
    int id = blockIdx.x * 256 + threadIdx.x;
    if (id < 8192) {                       // W_node: 16 nb x 8 kb x 64 lanes
        int l = id & 63, kb = (id >> 6) & 7, nb = id >> 9;
        int col = nb * 16 + (l & 15);
        int k0 = kb * 32 + (l >> 4) * 8;
        half8 v;
        #pragma unroll
        for (int j = 0; j < 8; ++j) v[j] = (_Float16)Wn[(size_t)(k0 + j) * OUT + col];
        ((half8*)Wp)[id] = v;
    } else if (id < 9216) {                // W_neigh: 16 nb x 64 lanes (K=32 pad)
        int id2 = id - 8192;
        int l = id2 & 63, nb = id2 >> 6;
        int col = nb * 16 + (l & 15);
        int k0 = (l >> 4) * 8;
        half8 v;
        #pragma unroll
        for (int j = 0; j < 8; ++j) {
            int k = k0 + j;
            v[j] = (k < HIDDEN) ? (_Float16)Wng[(size_t)k * OUT + col] : (_Float16)0.f;
        }
        ((half8*)Wnp)[id2] = v;
    } else if (id < 9728) {                // W_agg: 1 nb (16 cols) x 8 kb x 64 lanes
        int id3 = id - 9216;
        int l = id3 & 63, kb = id3 >> 6;
        int col = l & 15;
        int k0 = kb * 32 + (l >> 4) * 8;
        half8 v;
        #pragma unroll
        for (int j = 0; j < 8; ++j) v[j] = (_Float16)Wag[(size_t)(k0 + j) * HIDDEN + col];
        ((half8*)Wap)[id3] = v;
    }
}

// K1: per 32-node tile (3125 blocks), MFMA h = x@W_node (+bias -> packed f16
// parked in out's neigh half) AND h_agg = x@W_agg (wave 0 -> hpk, zero plane 4).
// acc[2][4] = 32 AGPRs -> ~4 waves/SIMD (vs 18% occupancy at acc[4][4]).
__global__ __launch_bounds__(256) void k_gemm(
    const float* __restrict__ x, const _Float16* __restrict__ Wp,
    const _Float16* __restrict__ Wap, const float* __restrict__ b_node,
    const float* __restrict__ b_agg, unsigned* __restrict__ hpk,
    unsigned* __restrict__ aencP, unsigned* __restrict__ gcnt,
    float* __restrict__ out)
{
    __shared__ unsigned short eagg[32][18];

    int t = threadIdx.x;
    if (blockIdx.x == 0 && t < NBUK) gcnt[t] = 0u;

    int w = t >> 6, l = t & 63, lr = l & 15, lg = l >> 4;
    int base = blockIdx.x * 32;

    size_t arow[2];
    #pragma unroll
    for (int mb = 0; mb < 2; ++mb)
        arow[mb] = (size_t)(base + mb * 16 + lr) * D_FEAT + lg * 8;

    f32x4 acc[2][4];
    #pragma unroll
    for (int mb = 0; mb < 2; ++mb)
        #pragma unroll
        for (int nb = 0; nb < 4; ++nb) acc[mb][nb] = (f32x4){0.f, 0.f, 0.f, 0.f};
    f32x4 agga[2];
    #pragma unroll
    for (int mb = 0; mb < 2; ++mb) agga[mb] = (f32x4){0.f, 0.f, 0.f, 0.f};

    const half8* WpV = (const half8*)Wp;
    const half8* WaV = (const half8*)Wap;

    #pragma unroll
    for (int kb = 0; kb < 8; ++kb) {
        half8 a[2];
        #pragma unroll
        for (int mb = 0; mb < 2; ++mb) {
            const float4* p = (const float4*)(x + arow[mb] + kb * 32);
            float4 u = p[0], v = p[1];
            half8 h;
            h[0]=(_Float16)u.x; h[1]=(_Float16)u.y; h[2]=(_Float16)u.z; h[3]=(_Float16)u.w;
            h[4]=(_Float16)v.x; h[5]=(_Float16)v.y; h[6]=(_Float16)v.z; h[7]=(_Float16)v.w;
            a[mb] = h;
        }
        half8 b[4];
        #pragma unroll
        for (int nb = 0; nb < 4; ++nb)
            b[nb] = WpV[((w * 4 + nb) * 8 + kb) * 64 + l];
        if (w == 0) {
            half8 bg = WaV[kb * 64 + l];
            #pragma unroll
            for (int mb = 0; mb < 2; ++mb)
                agga[mb] = __builtin_amdgcn_mfma_f32_16x16x32_f16(a[mb], bg, agga[mb], 0, 0, 0);
        }
        #pragma unroll
        for (int mb = 0; mb < 2; ++mb)
            #pragma unroll
            for (int nb = 0; nb < 4; ++nb)
                acc[mb][nb] = __builtin_amdgcn_mfma_f32_16x16x32_f16(
                    a[mb], b[nb], acc[mb][nb], 0, 0, 0);
    }

    // wave 0: bias + encode h_agg into LDS (rows 0..31)
    if (w == 0) {
        float ba = b_agg[lr];
        #pragma unroll
        for (int mb = 0; mb < 2; ++mb)
            #pragma unroll
            for (int r = 0; r < 4; ++r) {
                float val = agga[mb][r] + ba;
                eagg[mb * 16 + lg * 4 + r][lr] =
                    enc16(__builtin_bit_cast(unsigned short, (_Float16)val));
            }
    }
    __syncthreads();

    // pack pairs -> hpk; zero fallback plane 4 (1 word per thread)
    {
        int node = t >> 3, p = t & 7;
        int gn = base + node;
        unsigned lo = eagg[node][2 * p], hi = eagg[node][2 * p + 1];
        unsigned word = lo | (hi << 16);
        size_t idx = (size_t)gn * 8 + p;
        hpk[idx] = word;
        aencP[(size_t)NPLANE * PLANE + idx] = 0u;
    }

    // bias + pack h (32 values) to f16, park in out's neigh half:
    // thread t -> row base + (t>>3), bytes (t&7)*64 .. +64 of that row's neigh half
    float bnc[4];
    #pragma unroll
    for (int nb = 0; nb < 4; ++nb) bnc[nb] = b_node[w * 64 + nb * 16 + lr];
    half8 hv8[4];
    #pragma unroll
    for (int mb = 0; mb < 2; ++mb)
        #pragma unroll
        for (int nb = 0; nb < 4; ++nb)
            #pragma unroll
            for (int r = 0; r < 4; ++r) {
                int idx = mb * 16 + nb * 4 + r;
                hv8[idx >> 3][idx & 7] = (_Float16)(acc[mb][nb][r] + bnc[nb]);
            }
    char* hb = (char*)out + (size_t)(base + (t >> 3)) * 2048 + 1024 + (size_t)(t & 7) * 64;
    #pragma unroll
    for (int i = 0; i < 4; ++i)
        ((half8*)hb)[i] = hv8[i];
}

// Phase 1: bin edges into 196 per-bucket global lists via LDS staging.
// Entry u32 = src<<9 | (dst & 511). 800 blocks x 4000 edges.
__global__ __launch_bounds__(256) void k_bin(
    const int* __restrict__ src, const int* __restrict__ dst,
    const unsigned* __restrict__ hpk,
    unsigned* __restrict__ gbin, unsigned* __restrict__ gcnt,
    unsigned* __restrict__ a4)
{
    __shared__ unsigned lbuf[NBUK * 64];   // 50 KB
    __shared__ unsigned lcnt[NBUK];
    __shared__ unsigned gbase[NBUK];
    int t = threadIdx.x;
    for (int i = t; i < NBUK; i += 256) lcnt[i] = 0u;
    __syncthreads();

    int start = blockIdx.x * 4000;
    #pragma unroll 4
    for (int it = 0; it < 16; ++it) {
        int j = it * 256 + t;
        if (j < 4000) {
            int idx = start + j;
            int sv = src[idx], dv = dst[idx];
            int bk = dv >> 9;
            unsigned ev = ((unsigned)sv << 9) | (unsigned)(dv & 511);
            unsigned r = atomicAdd(&lcnt[bk], 1u);
            if (r < 64) lbuf[bk * 64 + r] = ev;
            else fb_cas(hpk, a4, sv, dv);      // ~1e-13 probability path
        }
    }
    __syncthreads();

    if (t < NBUK) {
        unsigned c = lcnt[t]; if (c > 64) c = 64;
        gbase[t] = atomicAdd(&gcnt[t], c);
    }
    __syncthreads();

    int wv = t >> 6, ln = t & 63;
    for (int b = wv; b < NBUK; b += 4) {
        unsigned c = lcnt[b]; if (c > 64) c = 64;
        if (ln < (int)c) {
            unsigned pos = gbase[b] + (unsigned)ln;
            unsigned ev = lbuf[b * 64 + ln];
            if (pos < CAP_G) gbin[(size_t)b * CAP_G + pos] = ev;
            else fb_cas(hpk, a4, (int)(ev >> 9), b * BSZ + (int)(ev & 511));
        }
    }
}

// Phase 2: per (bucket, plane) block — LDS segment-max. Gather hpk (L2-resident,
// read-only), atomicMax in LDS (17-padded), write plane coalesced. NO global atomics.
__global__ __launch_bounds__(256) void k_bucket(
    const unsigned* __restrict__ gbin, const unsigned* __restrict__ gcnt,
    const unsigned* __restrict__ hpk, unsigned* __restrict__ aencP)
{
    __shared__ unsigned tab[BSZ * 17];   // 34.8 KB
    int t = threadIdx.x;
    int b = blockIdx.x % NBUK;
    int k = blockIdx.x / NBUK;           // 0..3
    for (int i = t; i < BSZ * 17; i += 256) tab[i] = 0u;
    __syncthreads();

    int cnt = (int)gcnt[b]; if (cnt > CAP_G) cnt = CAP_G;
    int s = (cnt * k) >> 2;
    int e = (cnt * (k + 1)) >> 2;
    int p = t & 7;
    for (int i = s + (t >> 3); i < e; i += 32) {
        unsigned ev = gbin[(size_t)b * CAP_G + i];
        int srcn = (int)(ev >> 9), ld = (int)(ev & 511);
        unsigned pair = hpk[(size_t)srcn * 8 + p];
        atomicMax(&tab[ld * 17 + 2 * p], pair & 0xFFFFu);
        atomicMax(&tab[ld * 17 + 2 * p + 1], pair >> 16);
    }
    __syncthreads();

    for (int j = t; j < BSZ * 8; j += 256) {
        int n = j >> 3, pp = j & 7;
        int gn = b * BSZ + n;
        if (gn < N_NODES) {
            unsigned wd = tab[n * 17 + 2 * pp] | (tab[n * 17 + 2 * pp + 1] << 16);
            aencP[(size_t)k * PLANE + (size_t)gn * 8 + pp] = wd;
        }
    }
}

// K3 (32-row tiles, mirrors k_gemm thread mapping): merge 5 planes, decode agg
// -> LDS, load parked h, neighbour MFMA, l2-normalize concat, store.
__global__ __launch_bounds__(256) void k_epi(
    const unsigned* __restrict__ aencP, const _Float16* __restrict__ Wnp,
    const float* __restrict__ b_neigh, float* __restrict__ out)
{
    __shared__ _Float16 aggL[32][40];
    __shared__ float ss[4][32];
    __shared__ float invl[32];

    int t = threadIdx.x;
    int w = t >> 6, l = t & 63, lr = l & 15, lg = l >> 4;
    int base = blockIdx.x * 32;

    // merge planes + decode agg tile (32 nodes x 8 words; 1 word/thread)
    {
        int nl = t >> 3, p = t & 7;
        int gn = base + nl;
        size_t idx = (size_t)gn * 8 + p;
        unsigned v = 0u;
        #pragma unroll
        for (int k5 = 0; k5 <= NPLANE; ++k5)
            v = pmax16x2(v, aencP[(size_t)k5 * PLANE + idx]);
        aggL[nl][2 * p]     = dec16((unsigned short)(v & 0xFFFFu));
        aggL[nl][2 * p + 1] = dec16((unsigned short)(v >> 16));
    }
    for (int i = t; i < 32 * 16; i += 256)
        aggL[i >> 4][16 + (i & 15)] = (_Float16)0.f;

    // load this thread's parked h (same mapping as k_gemm thread t)
    const char* hb = (const char*)out + (size_t)(base + (t >> 3)) * 2048 + 1024 + (size_t)(t & 7) * 64;
    half8 hv8[4];
    #pragma unroll
    for (int i = 0; i < 4; ++i)
        hv8[i] = ((const half8*)hb)[i];

    __syncthreads();

    // neighbour layer: one MFMA per (mb,nb), K=32 (upper 16 zero-padded)
    f32x4 nacc[2][4];
    {
        half8 an[2], bn[4];
        #pragma unroll
        for (int mb = 0; mb < 2; ++mb)
            an[mb] = *(const half8*)(&aggL[mb * 16 + lr][lg * 8]);
        #pragma unroll
        for (int nb = 0; nb < 4; ++nb)
            bn[nb] = ((const half8*)Wnp)[(w * 4 + nb) * 64 + l];
        f32x4 z = (f32x4){0.f, 0.f, 0.f, 0.f};
        #pragma unroll
        for (int mb = 0; mb < 2; ++mb)
            #pragma unroll
            for (int nb = 0; nb < 4; ++nb)
                nacc[mb][nb] = __builtin_amdgcn_mfma_f32_16x16x32_f16(
                    an[mb], bn[nb], z, 0, 0, 0);
    }

    float bec[4];
    #pragma unroll
    for (int nb = 0; nb < 4; ++nb) bec[nb] = b_neigh[w * 64 + nb * 16 + lr];
    #pragma unroll
    for (int mb = 0; mb < 2; ++mb)
        #pragma unroll
        for (int nb = 0; nb < 4; ++nb)
            #pragma unroll
            for (int r = 0; r < 4; ++r)
                nacc[mb][nb][r] += bec[nb];

    // sum of squares per node row
    #pragma unroll
    for (int mb = 0; mb < 2; ++mb) {
        float p[4] = {0.f, 0.f, 0.f, 0.f};
        #pragma unroll
        for (int nb = 0; nb < 4; ++nb)
            #pragma unroll
            for (int r = 0; r < 4; ++r) {
                int idx = mb * 16 + nb * 4 + r;
                float hf = (float)hv8[idx >> 3][idx & 7];
                p[r] += hf * hf + nacc[mb][nb][r] * nacc[mb][nb][r];
            }
        #pragma unroll
        for (int r = 0; r < 4; ++r) {
            float v = p[r];
            v += __shfl_xor(v, 1);
            v += __shfl_xor(v, 2);
            v += __shfl_xor(v, 4);
            v += __shfl_xor(v, 8);
            if (lr == 0) ss[w][mb * 16 + lg * 4 + r] = v;
        }
    }
    __syncthreads();
    if (t < 32) {
        float sq = ss[0][t] + ss[1][t] + ss[2][t] + ss[3][t];
        invl[t] = rsqrtf(fmaxf(sq, 1e-12f));
    }
    __syncthreads();

    #pragma unroll
    for (int mb = 0; mb < 2; ++mb)
        #pragma unroll
        for (int r = 0; r < 4; ++r) {
            int slot = mb * 16 + lg * 4 + r;
            int node = base + slot;
            float inv = invl[slot];
            size_t row = (size_t)node * (2 * OUT);
            #pragma unroll
            for (int nb = 0; nb < 4; ++nb) {
                int col = w * 64 + nb * 16 + lr;
                int idx = mb * 16 + nb * 4 + r;
                out[row + col] = (float)hv8[idx >> 3][idx & 7] * inv;
                out[row + OUT + col] = nacc[mb][nb][r] * inv;
            }
        }
}

extern "C" void kernel_launch(void* const* d_in, const int* in_sizes, int n_in,
                              void* d_out, int out_size, void* d_ws, size_t ws_size,
                              hipStream_t stream) {
    const float* x       = (const float*)d_in[0];
    const int*   src     = (const int*)d_in[1];
    const int*   dst     = (const int*)d_in[2];
    const float* W_node  = (const float*)d_in[3];
    const float* b_node  = (const float*)d_in[4];
    const float* W_agg   = (const float*)d_in[5];
    const float* b_agg   = (const float*)d_in[6];
    const float* W_neigh = (const float*)d_in[7];
    const float* b_neigh = (const float*)d_in[8];
    float* out = (float*)d_out;

    char* ws = (char*)d_ws;
    unsigned*  hpk   = (unsigned*)ws;      ws += (size_t)N_NODES * 8 * 4;          // 3.2 MB
    unsigned*  aencP = (unsigned*)ws;      ws += (size_t)(NPLANE + 1) * PLANE * 4; // 16 MB
    unsigned*  gbin  = (unsigned*)ws;      ws += (size_t)NBUK * CAP_G * 4;         // 16.1 MB
    unsigned*  gcnt  = (unsigned*)ws;      ws += 1024;
    _Float16*  Wp    = (_Float16*)ws;      ws += (size_t)16 * 8 * 64 * 8 * 2;
    _Float16*  Wnp   = (_Float16*)ws;      ws += (size_t)16 * 64 * 8 * 2;
    _Float16*  Wap   = (_Float16*)ws;

    unsigned* a4 = aencP + (size_t)NPLANE * PLANE;

    k_pack<<<38, 256, 0, stream>>>(W_node, W_neigh, W_agg, Wp, Wnp, Wap);

    k_gemm<<<N_TILES, 256, 0, stream>>>(x, Wp, Wap, b_node, b_agg,
                                        hpk, aencP, gcnt, out);

    k_bin<<<800, 256, 0, stream>>>(src, dst, hpk, gbin, gcnt, a4);

    k_bucket<<<NBUK * NPLANE, 256, 0, stream>>>(gbin, gcnt, hpk, aencP);

    k_epi<<<N_TILES, 256, 0, stream>>>(aencP, Wnp, b_neigh, out);
}

// Round 18
// 228.135 us; speedup vs baseline: 1.8650x; 1.1240x over previous
//
#include <hip/hip_runtime.h>

#define N_NODES 100000
#define N_EDGES 3200000
#define D_FEAT 256
#define HIDDEN 16
#define OUT 256
#define N_TILES 3125                  // N_NODES / 32 exactly
#define PLANE ((size_t)N_NODES * 8)   // u32 words per aenc plane
#define NBUK 196                      // node buckets of 512
#define BSZ 512
#define CAP_G 20480                   // per-bucket global list capacity (mean 16.3K)
#define NPLANE 4                      // k_bucket planes; plane 4 = CAS fallback

typedef __attribute__((ext_vector_type(8))) _Float16 half8;
typedef __attribute__((ext_vector_type(4))) float f32x4;

__device__ __forceinline__ unsigned umax32(unsigned a, unsigned b) { return a > b ? a : b; }
__device__ __forceinline__ unsigned pmax16x2(unsigned a, unsigned b) {
    return umax32(a & 0xFFFFu, b & 0xFFFFu) | (umax32(a >> 16, b >> 16) << 16);
}

// Monotone f16-bits <-> u16 mapping: encoded compare == float compare.
__device__ __forceinline__ unsigned short enc16(unsigned short u) {
    return (u & 0x8000) ? (unsigned short)~u : (unsigned short)(u | 0x8000);
}
__device__ __forceinline__ _Float16 dec16(unsigned short e) {
    if (e == 0) return (_Float16)0.f;   // sentinel: no in-edge -> 0
    unsigned short b = (e & 0x8000) ? (unsigned short)(e & 0x7FFF) : (unsigned short)~e;
    return __builtin_bit_cast(_Float16, b);
}

// Rare-path: correct device-scope CAS-max into fallback plane 4.
__device__ __noinline__ void fb_cas(const unsigned* hpk, unsigned* a4, int sv, int dv) {
    #pragma unroll
    for (int p = 0; p < 8; ++p) {
        unsigned mine = hpk[(size_t)sv * 8 + p];
        unsigned* addr = a4 + (size_t)dv * 8 + p;
        unsigned cur = *addr;
        unsigned nv = pmax16x2(cur, mine);
        while (nv != cur) {
            unsigned old = atomicCAS(addr, cur, nv);
            if (old == cur) break;
            cur = old;
            nv = pmax16x2(cur, mine);
        }
    }
}

// Pack W_node, W_neigh, W_agg into MFMA B-fragment layout (f16). 38 blocks.
__global__ void k_pack(const float* __restrict__ Wn, const float* __restrict__ Wng,
                       const float* __restrict__ Wag,
                       _Float16* __restrict__ Wp, _Float16* __restrict__ Wnp,
                       _Float16* __restrict__ Wap)
{
    int id = blockIdx.x * 256 + threadIdx.x;
    if (id < 8192) {                       // W_node: 16 nb x 8 kb x 64 lanes
        int l = id & 63, kb = (id >> 6) & 7, nb = id >> 9;
        int col = nb * 16 + (l & 15);
        int k0 = kb * 32 + (l >> 4) * 8;
        half8 v;
        #pragma unroll
        for (int j = 0; j < 8; ++j) v[j] = (_Float16)Wn[(size_t)(k0 + j) * OUT + col];
        ((half8*)Wp)[id] = v;
    } else if (id < 9216) {                // W_neigh: 16 nb x 64 lanes (K=32 pad)
        int id2 = id - 8192;
        int l = id2 & 63, nb = id2 >> 6;
        int col = nb * 16 + (l & 15);
        int k0 = (l >> 4) * 8;
        half8 v;
        #pragma unroll
        for (int j = 0; j < 8; ++j) {
            int k = k0 + j;
            v[j] = (k < HIDDEN) ? (_Float16)Wng[(size_t)k * OUT + col] : (_Float16)0.f;
        }
        ((half8*)Wnp)[id2] = v;
    } else if (id < 9728) {                // W_agg: 1 nb (16 cols) x 8 kb x 64 lanes
        int id3 = id - 9216;
        int l = id3 & 63, kb = id3 >> 6;
        int col = l & 15;
        int k0 = kb * 32 + (l >> 4) * 8;
        half8 v;
        #pragma unroll
        for (int j = 0; j < 8; ++j) v[j] = (_Float16)Wag[(size_t)(k0 + j) * HIDDEN + col];
        ((half8*)Wap)[id3] = v;
    }
}

// K1 (R15-exact): per 32-node tile, MFMA h = x@W_node (+bias -> packed f16
// parked in out's neigh half) AND h_agg = x@W_agg (wave 0 -> hpk, zero plane 4).
__global__ __launch_bounds__(256) void k_gemm(
    const float* __restrict__ x, const _Float16* __restrict__ Wp,
    const _Float16* __restrict__ Wap, const float* __restrict__ b_node,
    const float* __restrict__ b_agg, unsigned* __restrict__ hpk,
    unsigned* __restrict__ aencP, unsigned* __restrict__ gcnt,
    float* __restrict__ out)
{
    __shared__ unsigned short eagg[32][18];

    int t = threadIdx.x;
    if (blockIdx.x == 0 && t < NBUK) gcnt[t] = 0u;

    int w = t >> 6, l = t & 63, lr = l & 15, lg = l >> 4;
    int base = blockIdx.x * 32;

    size_t arow[2];
    #pragma unroll
    for (int mb = 0; mb < 2; ++mb)
        arow[mb] = (size_t)(base + mb * 16 + lr) * D_FEAT + lg * 8;

    f32x4 acc[2][4];
    #pragma unroll
    for (int mb = 0; mb < 2; ++mb)
        #pragma unroll
        for (int nb = 0; nb < 4; ++nb) acc[mb][nb] = (f32x4){0.f, 0.f, 0.f, 0.f};
    f32x4 agga[2];
    #pragma unroll
    for (int mb = 0; mb < 2; ++mb) agga[mb] = (f32x4){0.f, 0.f, 0.f, 0.f};

    const half8* WpV = (const half8*)Wp;
    const half8* WaV = (const half8*)Wap;

    #pragma unroll
    for (int kb = 0; kb < 8; ++kb) {
        half8 a[2];
        #pragma unroll
        for (int mb = 0; mb < 2; ++mb) {
            const float4* p = (const float4*)(x + arow[mb] + kb * 32);
            float4 u = p[0], v = p[1];
            half8 h;
            h[0]=(_Float16)u.x; h[1]=(_Float16)u.y; h[2]=(_Float16)u.z; h[3]=(_Float16)u.w;
            h[4]=(_Float16)v.x; h[5]=(_Float16)v.y; h[6]=(_Float16)v.z; h[7]=(_Float16)v.w;
            a[mb] = h;
        }
        half8 b[4];
        #pragma unroll
        for (int nb = 0; nb < 4; ++nb)
            b[nb] = WpV[((w * 4 + nb) * 8 + kb) * 64 + l];
        if (w == 0) {
            half8 bg = WaV[kb * 64 + l];
            #pragma unroll
            for (int mb = 0; mb < 2; ++mb)
                agga[mb] = __builtin_amdgcn_mfma_f32_16x16x32_f16(a[mb], bg, agga[mb], 0, 0, 0);
        }
        #pragma unroll
        for (int mb = 0; mb < 2; ++mb)
            #pragma unroll
            for (int nb = 0; nb < 4; ++nb)
                acc[mb][nb] = __builtin_amdgcn_mfma_f32_16x16x32_f16(
                    a[mb], b[nb], acc[mb][nb], 0, 0, 0);
    }

    // wave 0: bias + encode h_agg into LDS (rows 0..31)
    if (w == 0) {
        float ba = b_agg[lr];
        #pragma unroll
        for (int mb = 0; mb < 2; ++mb)
            #pragma unroll
            for (int r = 0; r < 4; ++r) {
                float val = agga[mb][r] + ba;
                eagg[mb * 16 + lg * 4 + r][lr] =
                    enc16(__builtin_bit_cast(unsigned short, (_Float16)val));
            }
    }
    __syncthreads();

    // pack pairs -> hpk; zero fallback plane 4 (1 word per thread)
    {
        int node = t >> 3, p = t & 7;
        int gn = base + node;
        unsigned lo = eagg[node][2 * p], hi = eagg[node][2 * p + 1];
        unsigned word = lo | (hi << 16);
        size_t idx = (size_t)gn * 8 + p;
        hpk[idx] = word;
        aencP[(size_t)NPLANE * PLANE + idx] = 0u;
    }

    // bias + pack h (32 values) to f16, park in out's neigh half:
    // thread t -> row base + (t>>3), bytes (t&7)*64 .. +64 of that row's neigh half
    float bnc[4];
    #pragma unroll
    for (int nb = 0; nb < 4; ++nb) bnc[nb] = b_node[w * 64 + nb * 16 + lr];
    half8 hv8[4];
    #pragma unroll
    for (int mb = 0; mb < 2; ++mb)
        #pragma unroll
        for (int nb = 0; nb < 4; ++nb)
            #pragma unroll
            for (int r = 0; r < 4; ++r) {
                int idx = mb * 16 + nb * 4 + r;
                hv8[idx >> 3][idx & 7] = (_Float16)(acc[mb][nb][r] + bnc[nb]);
            }
    char* hb = (char*)out + (size_t)(base + (t >> 3)) * 2048 + 1024 + (size_t)(t & 7) * 64;
    #pragma unroll
    for (int i = 0; i < 4; ++i)
        ((half8*)hb)[i] = hv8[i];
}

// Phase 1 (R15-exact): bin edges into 196 per-bucket global lists via LDS
// staging. Entry u32 = src<<9 | (dst & 511). 800 blocks x 4000 edges.
__global__ __launch_bounds__(256) void k_bin(
    const int* __restrict__ src, const int* __restrict__ dst,
    const unsigned* __restrict__ hpk,
    unsigned* __restrict__ gbin, unsigned* __restrict__ gcnt,
    unsigned* __restrict__ a4)
{
    __shared__ unsigned lbuf[NBUK * 64];   // 50 KB
    __shared__ unsigned lcnt[NBUK];
    __shared__ unsigned gbase[NBUK];
    int t = threadIdx.x;
    for (int i = t; i < NBUK; i += 256) lcnt[i] = 0u;
    __syncthreads();

    int start = blockIdx.x * 4000;
    #pragma unroll 4
    for (int it = 0; it < 16; ++it) {
        int j = it * 256 + t;
        if (j < 4000) {
            int idx = start + j;
            int sv = src[idx], dv = dst[idx];
            int bk = dv >> 9;
            unsigned ev = ((unsigned)sv << 9) | (unsigned)(dv & 511);
            unsigned r = atomicAdd(&lcnt[bk], 1u);
            if (r < 64) lbuf[bk * 64 + r] = ev;
            else fb_cas(hpk, a4, sv, dv);      // ~1e-13 probability path
        }
    }
    __syncthreads();

    if (t < NBUK) {
        unsigned c = lcnt[t]; if (c > 64) c = 64;
        gbase[t] = atomicAdd(&gcnt[t], c);
    }
    __syncthreads();

    int wv = t >> 6, ln = t & 63;
    for (int b = wv; b < NBUK; b += 4) {
        unsigned c = lcnt[b]; if (c > 64) c = 64;
        if (ln < (int)c) {
            unsigned pos = gbase[b] + (unsigned)ln;
            unsigned ev = lbuf[b * 64 + ln];
            if (pos < CAP_G) gbin[(size_t)b * CAP_G + pos] = ev;
            else fb_cas(hpk, a4, (int)(ev >> 9), b * BSZ + (int)(ev & 511));
        }
    }
}

// Phase 2: per (bucket, plane) block — LDS segment-max. 4x-unrolled gather
// (MLP depth 4) + LDS pre-check (tab is monotone within the kernel, so a
// stale-read skip is always correct). No global atomics.
__global__ __launch_bounds__(256) void k_bucket(
    const unsigned* __restrict__ gbin, const unsigned* __restrict__ gcnt,
    const unsigned* __restrict__ hpk, unsigned* __restrict__ aencP)
{
    __shared__ unsigned tab[BSZ * 17];   // 34.8 KB
    int t = threadIdx.x;
    int b = blockIdx.x % NBUK;
    int k = blockIdx.x / NBUK;           // 0..3
    for (int i = t; i < BSZ * 17; i += 256) tab[i] = 0u;
    __syncthreads();

    int cnt = (int)gcnt[b]; if (cnt > CAP_G) cnt = CAP_G;
    int s = (cnt * k) >> 2;
    int e = (cnt * (k + 1)) >> 2;
    int p = t & 7;
    const unsigned* gb = gbin + (size_t)b * CAP_G;

    int i = s + (t >> 3);
    for (; i + 96 < e; i += 128) {
        unsigned ev0 = gb[i], ev1 = gb[i + 32], ev2 = gb[i + 64], ev3 = gb[i + 96];
        unsigned p0 = hpk[(size_t)(ev0 >> 9) * 8 + p];
        unsigned p1 = hpk[(size_t)(ev1 >> 9) * 8 + p];
        unsigned p2 = hpk[(size_t)(ev2 >> 9) * 8 + p];
        unsigned p3 = hpk[(size_t)(ev3 >> 9) * 8 + p];
        {
            int a0 = (int)(ev0 & 511) * 17 + 2 * p;
            unsigned lo = p0 & 0xFFFFu, hi = p0 >> 16;
            if (lo > tab[a0])     atomicMax(&tab[a0], lo);
            if (hi > tab[a0 + 1]) atomicMax(&tab[a0 + 1], hi);
        }
        {
            int a1 = (int)(ev1 & 511) * 17 + 2 * p;
            unsigned lo = p1 & 0xFFFFu, hi = p1 >> 16;
            if (lo > tab[a1])     atomicMax(&tab[a1], lo);
            if (hi > tab[a1 + 1]) atomicMax(&tab[a1 + 1], hi);
        }
        {
            int a2 = (int)(ev2 & 511) * 17 + 2 * p;
            unsigned lo = p2 & 0xFFFFu, hi = p2 >> 16;
            if (lo > tab[a2])     atomicMax(&tab[a2], lo);
            if (hi > tab[a2 + 1]) atomicMax(&tab[a2 + 1], hi);
        }
        {
            int a3 = (int)(ev3 & 511) * 17 + 2 * p;
            unsigned lo = p3 & 0xFFFFu, hi = p3 >> 16;
            if (lo > tab[a3])     atomicMax(&tab[a3], lo);
            if (hi > tab[a3 + 1]) atomicMax(&tab[a3 + 1], hi);
        }
    }
    for (; i < e; i += 32) {
        unsigned ev = gb[i];
        unsigned pair = hpk[(size_t)(ev >> 9) * 8 + p];
        int a0 = (int)(ev & 511) * 17 + 2 * p;
        unsigned lo = pair & 0xFFFFu, hi = pair >> 16;
        if (lo > tab[a0])     atomicMax(&tab[a0], lo);
        if (hi > tab[a0 + 1]) atomicMax(&tab[a0 + 1], hi);
    }
    __syncthreads();

    for (int j = t; j < BSZ * 8; j += 256) {
        int n = j >> 3, pp = j & 7;
        int gn = b * BSZ + n;
        if (gn < N_NODES) {
            unsigned wd = tab[n * 17 + 2 * pp] | (tab[n * 17 + 2 * pp + 1] << 16);
            aencP[(size_t)k * PLANE + (size_t)gn * 8 + pp] = wd;
        }
    }
}

// K3 (R15-exact): merge 5 planes, decode agg -> LDS, load parked h,
// neighbour MFMA, l2-normalize concat, store.
__global__ __launch_bounds__(256) void k_epi(
    const unsigned* __restrict__ aencP, const _Float16* __restrict__ Wnp,
    const float* __restrict__ b_neigh, float* __restrict__ out)
{
    __shared__ _Float16 aggL[32][40];
    __shared__ float ss[4][32];
    __shared__ float invl[32];

    int t = threadIdx.x;
    int w = t >> 6, l = t & 63, lr = l & 15, lg = l >> 4;
    int base = blockIdx.x * 32;

    {
        int nl = t >> 3, p = t & 7;
        int gn = base + nl;
        size_t idx = (size_t)gn * 8 + p;
        unsigned v = 0u;
        #pragma unroll
        for (int k5 = 0; k5 <= NPLANE; ++k5)
            v = pmax16x2(v, aencP[(size_t)k5 * PLANE + idx]);
        aggL[nl][2 * p]     = dec16((unsigned short)(v & 0xFFFFu));
        aggL[nl][2 * p + 1] = dec16((unsigned short)(v >> 16));
    }
    for (int i = t; i < 32 * 16; i += 256)
        aggL[i >> 4][16 + (i & 15)] = (_Float16)0.f;

    const char* hb = (const char*)out + (size_t)(base + (t >> 3)) * 2048 + 1024 + (size_t)(t & 7) * 64;
    half8 hv8[4];
    #pragma unroll
    for (int i = 0; i < 4; ++i)
        hv8[i] = ((const half8*)hb)[i];

    __syncthreads();

    f32x4 nacc[2][4];
    {
        half8 an[2], bn[4];
        #pragma unroll
        for (int mb = 0; mb < 2; ++mb)
            an[mb] = *(const half8*)(&aggL[mb * 16 + lr][lg * 8]);
        #pragma unroll
        for (int nb = 0; nb < 4; ++nb)
            bn[nb] = ((const half8*)Wnp)[(w * 4 + nb) * 64 + l];
        f32x4 z = (f32x4){0.f, 0.f, 0.f, 0.f};
        #pragma unroll
        for (int mb = 0; mb < 2; ++mb)
            #pragma unroll
            for (int nb = 0; nb < 4; ++nb)
                nacc[mb][nb] = __builtin_amdgcn_mfma_f32_16x16x32_f16(
                    an[mb], bn[nb], z, 0, 0, 0);
    }

    float bec[4];
    #pragma unroll
    for (int nb = 0; nb < 4; ++nb) bec[nb] = b_neigh[w * 64 + nb * 16 + lr];
    #pragma unroll
    for (int mb = 0; mb < 2; ++mb)
        #pragma unroll
        for (int nb = 0; nb < 4; ++nb)
            #pragma unroll
            for (int r = 0; r < 4; ++r)
                nacc[mb][nb][r] += bec[nb];

    #pragma unroll
    for (int mb = 0; mb < 2; ++mb) {
        float p[4] = {0.f, 0.f, 0.f, 0.f};
        #pragma unroll
        for (int nb = 0; nb < 4; ++nb)
            #pragma unroll
            for (int r = 0; r < 4; ++r) {
                int idx = mb * 16 + nb * 4 + r;
                float hf = (float)hv8[idx >> 3][idx & 7];
                p[r] += hf * hf + nacc[mb][nb][r] * nacc[mb][nb][r];
            }
        #pragma unroll
        for (int r = 0; r < 4; ++r) {
            float v = p[r];
            v += __shfl_xor(v, 1);
            v += __shfl_xor(v, 2);
            v += __shfl_xor(v, 4);
            v += __shfl_xor(v, 8);
            if (lr == 0) ss[w][mb * 16 + lg * 4 + r] = v;
        }
    }
    __syncthreads();
    if (t < 32) {
        float sq = ss[0][t] + ss[1][t] + ss[2][t] + ss[3][t];
        invl[t] = rsqrtf(fmaxf(sq, 1e-12f));
    }
    __syncthreads();

    #pragma unroll
    for (int mb = 0; mb < 2; ++mb)
        #pragma unroll
        for (int r = 0; r < 4; ++r) {
            int slot = mb * 16 + lg * 4 + r;
            int node = base + slot;
            float inv = invl[slot];
            size_t row = (size_t)node * (2 * OUT);
            #pragma unroll
            for (int nb = 0; nb < 4; ++nb) {
                int col = w * 64 + nb * 16 + lr;
                int idx = mb * 16 + nb * 4 + r;
                out[row + col] = (float)hv8[idx >> 3][idx & 7] * inv;
                out[row + OUT + col] = nacc[mb][nb][r] * inv;
            }
        }
}

extern "C" void kernel_launch(void* const* d_in, const int* in_sizes, int n_in,
                              void* d_out, int out_size, void* d_ws, size_t ws_size,
                              hipStream_t stream) {
    const float* x       = (const float*)d_in[0];
    const int*   src     = (const int*)d_in[1];
    const int*   dst     = (const int*)d_in[2];
    const float* W_node  = (const float*)d_in[3];
    const float* b_node  = (const float*)d_in[4];
    const float* W_agg   = (const float*)d_in[5];
    const float* b_agg   = (const float*)d_in[6];
    const float* W_neigh = (const float*)d_in[7];
    const float* b_neigh = (const float*)d_in[8];
    float* out = (float*)d_out;

    char* ws = (char*)d_ws;
    unsigned*  hpk   = (unsigned*)ws;      ws += (size_t)N_NODES * 8 * 4;          // 3.2 MB
    unsigned*  aencP = (unsigned*)ws;      ws += (size_t)(NPLANE + 1) * PLANE * 4; // 16 MB
    unsigned*  gbin  = (unsigned*)ws;      ws += (size_t)NBUK * CAP_G * 4;         // 16.1 MB
    unsigned*  gcnt  = (unsigned*)ws;      ws += 1024;
    _Float16*  Wp    = (_Float16*)ws;      ws += (size_t)16 * 8 * 64 * 8 * 2;
    _Float16*  Wnp   = (_Float16*)ws;      ws += (size_t)16 * 64 * 8 * 2;
    _Float16*  Wap   = (_Float16*)ws;

    unsigned* a4 = aencP + (size_t)NPLANE * PLANE;

    k_pack<<<38, 256, 0, stream>>>(W_node, W_neigh, W_agg, Wp, Wnp, Wap);

    k_gemm<<<N_TILES, 256, 0, stream>>>(x, Wp, Wap, b_node, b_agg,
                                        hpk, aencP, gcnt, out);

    k_bin<<<800, 256, 0, stream>>>(src, dst, hpk, gbin, gcnt, a4);

    k_bucket<<<NBUK * NPLANE, 256, 0, stream>>>(gbin, gcnt, hpk, aencP);

    k_epi<<<N_TILES, 256, 0, stream>>>(aencP, Wnp, b_neigh, out);
}

// Round 19
// 189.546 us; speedup vs baseline: 2.2447x; 1.2036x over previous
//
#include <hip/hip_runtime.h>

#define N_NODES 100000
#define N_EDGES 3200000
#define D_FEAT 256
#define HIDDEN 16
#define OUT 256
#define N_TILES 3125                  // N_NODES / 32 exactly
#define PLANE ((size_t)N_NODES * 8)   // u32 words per aenc plane
#define NBUK 196                      // node buckets of 512
#define BSZ 512
#define CAP_G 20480                   // per-bucket global list capacity (mean 16.3K)
#define NPLANE 4                      // k_bucket planes; plane 4 = CAS fallback

typedef __attribute__((ext_vector_type(8))) _Float16 half8;
typedef __attribute__((ext_vector_type(4))) float f32x4;

__device__ __forceinline__ unsigned umax32(unsigned a, unsigned b) { return a > b ? a : b; }
__device__ __forceinline__ unsigned pmax16x2(unsigned a, unsigned b) {
    return umax32(a & 0xFFFFu, b & 0xFFFFu) | (umax32(a >> 16, b >> 16) << 16);
}

// Monotone f16-bits <-> u16 mapping: encoded compare == float compare.
__device__ __forceinline__ unsigned short enc16(unsigned short u) {
    return (u & 0x8000) ? (unsigned short)~u : (unsigned short)(u | 0x8000);
}
__device__ __forceinline__ _Float16 dec16(unsigned short e) {
    if (e == 0) return (_Float16)0.f;   // sentinel: no in-edge -> 0
    unsigned short b = (e & 0x8000) ? (unsigned short)(e & 0x7FFF) : (unsigned short)~e;
    return __builtin_bit_cast(_Float16, b);
}

// Rare-path: correct device-scope CAS-max into fallback plane 4.
__device__ __noinline__ void fb_cas(const unsigned* hpk, unsigned* a4, int sv, int dv) {
    #pragma unroll
    for (int p = 0; p < 8; ++p) {
        unsigned mine = hpk[(size_t)sv * 8 + p];
        unsigned* addr = a4 + (size_t)dv * 8 + p;
        unsigned cur = *addr;
        unsigned nv = pmax16x2(cur, mine);
        while (nv != cur) {
            unsigned old = atomicCAS(addr, cur, nv);
            if (old == cur) break;
            cur = old;
            nv = pmax16x2(cur, mine);
        }
    }
}

// Pack W_node, W_neigh, W_agg into MFMA B-fragment layout (f16). 38 blocks.
__global__ void k_pack(const float* __restrict__ Wn, const float* __restrict__ Wng,
                       const float* __restrict__ Wag,
                       _Float16* __restrict__ Wp, _Float16* __restrict__ Wnp,
                       _Float16* __restrict__ Wap)
{
    int id = blockIdx.x * 256 + threadIdx.x;
    if (id < 8192) {                       // W_node: 16 nb x 8 kb x 64 lanes
        int l = id & 63, kb = (id >> 6) & 7, nb = id >> 9;
        int col = nb * 16 + (l & 15);
        int k0 = kb * 32 + (l >> 4) * 8;
        half8 v;
        #pragma unroll
        for (int j = 0; j < 8; ++j) v[j] = (_Float16)Wn[(size_t)(k0 + j) * OUT + col];
        ((half8*)Wp)[id] = v;
    } else if (id < 9216) {                // W_neigh: 16 nb x 64 lanes (K=32 pad)
        int id2 = id - 8192;
        int l = id2 & 63, nb = id2 >> 6;
        int col = nb * 16 + (l & 15);
        int k0 = (l >> 4) * 8;
        half8 v;
        #pragma unroll
        for (int j = 0; j < 8; ++j) {
            int k = k0 + j;
            v[j] = (k < HIDDEN) ? (_Float16)Wng[(size_t)k * OUT + col] : (_Float16)0.f;
        }
        ((half8*)Wnp)[id2] = v;
    } else if (id < 9728) {                // W_agg: 1 nb (16 cols) x 8 kb x 64 lanes
        int id3 = id - 9216;
        int l = id3 & 63, kb = id3 >> 6;
        int col = l & 15;
        int k0 = kb * 32 + (l >> 4) * 8;
        half8 v;
        #pragma unroll
        for (int j = 0; j < 8; ++j) v[j] = (_Float16)Wag[(size_t)(k0 + j) * HIDDEN + col];
        ((half8*)Wap)[id3] = v;
    }
}

// K1 (R19): per 32-node tile. STAGE x tile (contiguous 32 KB) -> LDS as f16
// with coalesced streaming loads + in-flight convert, then MFMA h = x@W_node
// (+bias -> packed f16 parked in out's neigh half) AND h_agg = x@W_agg
// (wave 0 -> hpk, zero plane 4).
__global__ __launch_bounds__(256) void k_gemm(
    const float* __restrict__ x, const _Float16* __restrict__ Wp,
    const _Float16* __restrict__ Wap, const float* __restrict__ b_node,
    const float* __restrict__ b_agg, unsigned* __restrict__ hpk,
    unsigned* __restrict__ aencP, unsigned* __restrict__ gcnt,
    float* __restrict__ out)
{
    __shared__ _Float16 xs[32][256];       // 16 KB f16 tile
    __shared__ unsigned short eagg[32][18];

    int t = threadIdx.x;
    if (blockIdx.x == 0 && t < NBUK) gcnt[t] = 0u;

    int base = blockIdx.x * 32;

    // ---- stage + convert: thread t owns 32 consecutive floats of the tile
    {
        const float4* xg = (const float4*)(x + (size_t)base * D_FEAT) + (size_t)t * 8;
        float4 v[8];
        #pragma unroll
        for (int i = 0; i < 8; ++i) v[i] = xg[i];
        half8* dst = (half8*)(&xs[t >> 3][(t & 7) * 32]);
        #pragma unroll
        for (int i = 0; i < 4; ++i) {
            float4 u0 = v[2 * i], u1 = v[2 * i + 1];
            half8 h;
            h[0]=(_Float16)u0.x; h[1]=(_Float16)u0.y; h[2]=(_Float16)u0.z; h[3]=(_Float16)u0.w;
            h[4]=(_Float16)u1.x; h[5]=(_Float16)u1.y; h[6]=(_Float16)u1.z; h[7]=(_Float16)u1.w;
            dst[i] = h;
        }
    }
    __syncthreads();

    int w = t >> 6, l = t & 63, lr = l & 15, lg = l >> 4;

    f32x4 acc[2][4];
    #pragma unroll
    for (int mb = 0; mb < 2; ++mb)
        #pragma unroll
        for (int nb = 0; nb < 4; ++nb) acc[mb][nb] = (f32x4){0.f, 0.f, 0.f, 0.f};
    f32x4 agga[2];
    #pragma unroll
    for (int mb = 0; mb < 2; ++mb) agga[mb] = (f32x4){0.f, 0.f, 0.f, 0.f};

    const half8* WpV = (const half8*)Wp;
    const half8* WaV = (const half8*)Wap;

    #pragma unroll
    for (int kb = 0; kb < 8; ++kb) {
        half8 a[2];
        #pragma unroll
        for (int mb = 0; mb < 2; ++mb)
            a[mb] = *(const half8*)(&xs[mb * 16 + lr][kb * 32 + lg * 8]);
        half8 b[4];
        #pragma unroll
        for (int nb = 0; nb < 4; ++nb)
            b[nb] = WpV[((w * 4 + nb) * 8 + kb) * 64 + l];
        if (w == 0) {
            half8 bg = WaV[kb * 64 + l];
            #pragma unroll
            for (int mb = 0; mb < 2; ++mb)
                agga[mb] = __builtin_amdgcn_mfma_f32_16x16x32_f16(a[mb], bg, agga[mb], 0, 0, 0);
        }
        #pragma unroll
        for (int mb = 0; mb < 2; ++mb)
            #pragma unroll
            for (int nb = 0; nb < 4; ++nb)
                acc[mb][nb] = __builtin_amdgcn_mfma_f32_16x16x32_f16(
                    a[mb], b[nb], acc[mb][nb], 0, 0, 0);
    }

    // wave 0: bias + encode h_agg into LDS (rows 0..31)
    if (w == 0) {
        float ba = b_agg[lr];
        #pragma unroll
        for (int mb = 0; mb < 2; ++mb)
            #pragma unroll
            for (int r = 0; r < 4; ++r) {
                float val = agga[mb][r] + ba;
                eagg[mb * 16 + lg * 4 + r][lr] =
                    enc16(__builtin_bit_cast(unsigned short, (_Float16)val));
            }
    }
    __syncthreads();

    // pack pairs -> hpk; zero fallback plane 4 (1 word per thread)
    {
        int node = t >> 3, p = t & 7;
        int gn = base + node;
        unsigned lo = eagg[node][2 * p], hi = eagg[node][2 * p + 1];
        unsigned word = lo | (hi << 16);
        size_t idx = (size_t)gn * 8 + p;
        hpk[idx] = word;
        aencP[(size_t)NPLANE * PLANE + idx] = 0u;
    }

    // bias + pack h (32 values) to f16, park in out's neigh half:
    // thread t -> row base + (t>>3), bytes (t&7)*64 .. +64 of that row's neigh half
    float bnc[4];
    #pragma unroll
    for (int nb = 0; nb < 4; ++nb) bnc[nb] = b_node[w * 64 + nb * 16 + lr];
    half8 hv8[4];
    #pragma unroll
    for (int mb = 0; mb < 2; ++mb)
        #pragma unroll
        for (int nb = 0; nb < 4; ++nb)
            #pragma unroll
            for (int r = 0; r < 4; ++r) {
                int idx = mb * 16 + nb * 4 + r;
                hv8[idx >> 3][idx & 7] = (_Float16)(acc[mb][nb][r] + bnc[nb]);
            }
    char* hb = (char*)out + (size_t)(base + (t >> 3)) * 2048 + 1024 + (size_t)(t & 7) * 64;
    #pragma unroll
    for (int i = 0; i < 4; ++i)
        ((half8*)hb)[i] = hv8[i];
}

// Phase 1 (R15-exact): bin edges into 196 per-bucket global lists via LDS
// staging. Entry u32 = src<<9 | (dst & 511). 800 blocks x 4000 edges.
__global__ __launch_bounds__(256) void k_bin(
    const int* __restrict__ src, const int* __restrict__ dst,
    const unsigned* __restrict__ hpk,
    unsigned* __restrict__ gbin, unsigned* __restrict__ gcnt,
    unsigned* __restrict__ a4)
{
    __shared__ unsigned lbuf[NBUK * 64];   // 50 KB
    __shared__ unsigned lcnt[NBUK];
    __shared__ unsigned gbase[NBUK];
    int t = threadIdx.x;
    for (int i = t; i < NBUK; i += 256) lcnt[i] = 0u;
    __syncthreads();

    int start = blockIdx.x * 4000;
    #pragma unroll 4
    for (int it = 0; it < 16; ++it) {
        int j = it * 256 + t;
        if (j < 4000) {
            int idx = start + j;
            int sv = src[idx], dv = dst[idx];
            int bk = dv >> 9;
            unsigned ev = ((unsigned)sv << 9) | (unsigned)(dv & 511);
            unsigned r = atomicAdd(&lcnt[bk], 1u);
            if (r < 64) lbuf[bk * 64 + r] = ev;
            else fb_cas(hpk, a4, sv, dv);      // ~1e-13 probability path
        }
    }
    __syncthreads();

    if (t < NBUK) {
        unsigned c = lcnt[t]; if (c > 64) c = 64;
        gbase[t] = atomicAdd(&gcnt[t], c);
    }
    __syncthreads();

    int wv = t >> 6, ln = t & 63;
    for (int b = wv; b < NBUK; b += 4) {
        unsigned c = lcnt[b]; if (c > 64) c = 64;
        if (ln < (int)c) {
            unsigned pos = gbase[b] + (unsigned)ln;
            unsigned ev = lbuf[b * 64 + ln];
            if (pos < CAP_G) gbin[(size_t)b * CAP_G + pos] = ev;
            else fb_cas(hpk, a4, (int)(ev >> 9), b * BSZ + (int)(ev & 511));
        }
    }
}

// Phase 2 (R18-exact): per (bucket, plane) block — LDS segment-max.
// 4x-unrolled gather (MLP depth 4) + LDS pre-check (tab monotone -> stale-read
// skip always correct). No global atomics.
__global__ __launch_bounds__(256) void k_bucket(
    const unsigned* __restrict__ gbin, const unsigned* __restrict__ gcnt,
    const unsigned* __restrict__ hpk, unsigned* __restrict__ aencP)
{
    __shared__ unsigned tab[BSZ * 17];   // 34.8 KB
    int t = threadIdx.x;
    int b = blockIdx.x % NBUK;
    int k = blockIdx.x / NBUK;           // 0..3
    for (int i = t; i < BSZ * 17; i += 256) tab[i] = 0u;
    __syncthreads();

    int cnt = (int)gcnt[b]; if (cnt > CAP_G) cnt = CAP_G;
    int s = (cnt * k) >> 2;
    int e = (cnt * (k + 1)) >> 2;
    int p = t & 7;
    const unsigned* gb = gbin + (size_t)b * CAP_G;

    int i = s + (t >> 3);
    for (; i + 96 < e; i += 128) {
        unsigned ev0 = gb[i], ev1 = gb[i + 32], ev2 = gb[i + 64], ev3 = gb[i + 96];
        unsigned p0 = hpk[(size_t)(ev0 >> 9) * 8 + p];
        unsigned p1 = hpk[(size_t)(ev1 >> 9) * 8 + p];
        unsigned p2 = hpk[(size_t)(ev2 >> 9) * 8 + p];
        unsigned p3 = hpk[(size_t)(ev3 >> 9) * 8 + p];
        {
            int a0 = (int)(ev0 & 511) * 17 + 2 * p;
            unsigned lo = p0 & 0xFFFFu, hi = p0 >> 16;
            if (lo > tab[a0])     atomicMax(&tab[a0], lo);
            if (hi > tab[a0 + 1]) atomicMax(&tab[a0 + 1], hi);
        }
        {
            int a1 = (int)(ev1 & 511) * 17 + 2 * p;
            unsigned lo = p1 & 0xFFFFu, hi = p1 >> 16;
            if (lo > tab[a1])     atomicMax(&tab[a1], lo);
            if (hi > tab[a1 + 1]) atomicMax(&tab[a1 + 1], hi);
        }
        {
            int a2 = (int)(ev2 & 511) * 17 + 2 * p;
            unsigned lo = p2 & 0xFFFFu, hi = p2 >> 16;
            if (lo > tab[a2])     atomicMax(&tab[a2], lo);
            if (hi > tab[a2 + 1]) atomicMax(&tab[a2 + 1], hi);
        }
        {
            int a3 = (int)(ev3 & 511) * 17 + 2 * p;
            unsigned lo = p3 & 0xFFFFu, hi = p3 >> 16;
            if (lo > tab[a3])     atomicMax(&tab[a3], lo);
            if (hi > tab[a3 + 1]) atomicMax(&tab[a3 + 1], hi);
        }
    }
    for (; i < e; i += 32) {
        unsigned ev = gb[i];
        unsigned pair = hpk[(size_t)(ev >> 9) * 8 + p];
        int a0 = (int)(ev & 511) * 17 + 2 * p;
        unsigned lo = pair & 0xFFFFu, hi = pair >> 16;
        if (lo > tab[a0])     atomicMax(&tab[a0], lo);
        if (hi > tab[a0 + 1]) atomicMax(&tab[a0 + 1], hi);
    }
    __syncthreads();

    for (int j = t; j < BSZ * 8; j += 256) {
        int n = j >> 3, pp = j & 7;
        int gn = b * BSZ + n;
        if (gn < N_NODES) {
            unsigned wd = tab[n * 17 + 2 * pp] | (tab[n * 17 + 2 * pp + 1] << 16);
            aencP[(size_t)k * PLANE + (size_t)gn * 8 + pp] = wd;
        }
    }
}

// K3 (R15-exact): merge 5 planes, decode agg -> LDS, load parked h,
// neighbour MFMA, l2-normalize concat, store.
__global__ __launch_bounds__(256) void k_epi(
    const unsigned* __restrict__ aencP, const _Float16* __restrict__ Wnp,
    const float* __restrict__ b_neigh, float* __restrict__ out)
{
    __shared__ _Float16 aggL[32][40];
    __shared__ float ss[4][32];
    __shared__ float invl[32];

    int t = threadIdx.x;
    int w = t >> 6, l = t & 63, lr = l & 15, lg = l >> 4;
    int base = blockIdx.x * 32;

    {
        int nl = t >> 3, p = t & 7;
        int gn = base + nl;
        size_t idx = (size_t)gn * 8 + p;
        unsigned v = 0u;
        #pragma unroll
        for (int k5 = 0; k5 <= NPLANE; ++k5)
            v = pmax16x2(v, aencP[(size_t)k5 * PLANE + idx]);
        aggL[nl][2 * p]     = dec16((unsigned short)(v & 0xFFFFu));
        aggL[nl][2 * p + 1] = dec16((unsigned short)(v >> 16));
    }
    for (int i = t; i < 32 * 16; i += 256)
        aggL[i >> 4][16 + (i & 15)] = (_Float16)0.f;

    const char* hb = (const char*)out + (size_t)(base + (t >> 3)) * 2048 + 1024 + (size_t)(t & 7) * 64;
    half8 hv8[4];
    #pragma unroll
    for (int i = 0; i < 4; ++i)
        hv8[i] = ((const half8*)hb)[i];

    __syncthreads();

    f32x4 nacc[2][4];
    {
        half8 an[2], bn[4];
        #pragma unroll
        for (int mb = 0; mb < 2; ++mb)
            an[mb] = *(const half8*)(&aggL[mb * 16 + lr][lg * 8]);
        #pragma unroll
        for (int nb = 0; nb < 4; ++nb)
            bn[nb] = ((const half8*)Wnp)[(w * 4 + nb) * 64 + l];
        f32x4 z = (f32x4){0.f, 0.f, 0.f, 0.f};
        #pragma unroll
        for (int mb = 0; mb < 2; ++mb)
            #pragma unroll
            for (int nb = 0; nb < 4; ++nb)
                nacc[mb][nb] = __builtin_amdgcn_mfma_f32_16x16x32_f16(
                    an[mb], bn[nb], z, 0, 0, 0);
    }

    float bec[4];
    #pragma unroll
    for (int nb = 0; nb < 4; ++nb) bec[nb] = b_neigh[w * 64 + nb * 16 + lr];
    #pragma unroll
    for (int mb = 0; mb < 2; ++mb)
        #pragma unroll
        for (int nb = 0; nb < 4; ++nb)
            #pragma unroll
            for (int r = 0; r < 4; ++r)
                nacc[mb][nb][r] += bec[nb];

    #pragma unroll
    for (int mb = 0; mb < 2; ++mb) {
        float p[4] = {0.f, 0.f, 0.f, 0.f};
        #pragma unroll
        for (int nb = 0; nb < 4; ++nb)
            #pragma unroll
            for (int r = 0; r < 4; ++r) {
                int idx = mb * 16 + nb * 4 + r;
                float hf = (float)hv8[idx >> 3][idx & 7];
                p[r] += hf * hf + nacc[mb][nb][r] * nacc[mb][nb][r];
            }
        #pragma unroll
        for (int r = 0; r < 4; ++r) {
            float v = p[r];
            v += __shfl_xor(v, 1);
            v += __shfl_xor(v, 2);
            v += __shfl_xor(v, 4);
            v += __shfl_xor(v, 8);
            if (lr == 0) ss[w][mb * 16 + lg * 4 + r] = v;
        }
    }
    __syncthreads();
    if (t < 32) {
        float sq = ss[0][t] + ss[1][t] + ss[2][t] + ss[3][t];
        invl[t] = rsqrtf(fmaxf(sq, 1e-12f));
    }
    __syncthreads();

    #pragma unroll
    for (int mb = 0; mb < 2; ++mb)
        #pragma unroll
        for (int r = 0; r < 4; ++r) {
            int slot = mb * 16 + lg * 4 + r;
            int node = base + slot;
            float inv = invl[slot];
            size_t row = (size_t)node * (2 * OUT);
            #pragma unroll
            for (int nb = 0; nb < 4; ++nb) {
                int col = w * 64 + nb * 16 + lr;
                int idx = mb * 16 + nb * 4 + r;
                out[row + col] = (float)hv8[idx >> 3][idx & 7] * inv;
                out[row + OUT + col] = nacc[mb][nb][r] * inv;
            }
        }
}

extern "C" void kernel_launch(void* const* d_in, const int* in_sizes, int n_in,
                              void* d_out, int out_size, void* d_ws, size_t ws_size,
                              hipStream_t stream) {
    const float* x       = (const float*)d_in[0];
    const int*   src     = (const int*)d_in[1];
    const int*   dst     = (const int*)d_in[2];
    const float* W_node  = (const float*)d_in[3];
    const float* b_node  = (const float*)d_in[4];
    const float* W_agg   = (const float*)d_in[5];
    const float* b_agg   = (const float*)d_in[6];
    const float* W_neigh = (const float*)d_in[7];
    const float* b_neigh = (const float*)d_in[8];
    float* out = (float*)d_out;

    char* ws = (char*)d_ws;
    unsigned*  hpk   = (unsigned*)ws;      ws += (size_t)N_NODES * 8 * 4;          // 3.2 MB
    unsigned*  aencP = (unsigned*)ws;      ws += (size_t)(NPLANE + 1) * PLANE * 4; // 16 MB
    unsigned*  gbin  = (unsigned*)ws;      ws += (size_t)NBUK * CAP_G * 4;         // 16.1 MB
    unsigned*  gcnt  = (unsigned*)ws;      ws += 1024;
    _Float16*  Wp    = (_Float16*)ws;      ws += (size_t)16 * 8 * 64 * 8 * 2;
    _Float16*  Wnp   = (_Float16*)ws;      ws += (size_t)16 * 64 * 8 * 2;
    _Float16*  Wap   = (_Float16*)ws;

    unsigned* a4 = aencP + (size_t)NPLANE * PLANE;

    k_pack<<<38, 256, 0, stream>>>(W_node, W_neigh, W_agg, Wp, Wnp, Wap);

    k_gemm<<<N_TILES, 256, 0, stream>>>(x, Wp, Wap, b_node, b_agg,
                                        hpk, aencP, gcnt, out);

    k_bin<<<800, 256, 0, stream>>>(src, dst, hpk, gbin, gcnt, a4);

    k_bucket<<<NBUK * NPLANE, 256, 0, stream>>>(gbin, gcnt, hpk, aencP);

    k_epi<<<N_TILES, 256, 0, stream>>>(aencP, Wnp, b_neigh, out);
}